// Round 4
// baseline (1863.257 us; speedup 1.0000x reference)
//
#include <hip/hip_runtime.h>
#include <stdint.h>

#define NN 50000
#define NE 800000
#define STRIP 49   // ceil(NN/1024)

typedef unsigned int u32;
typedef uint16_t u16;

__device__ __forceinline__ float b2f(u16 u){ return __builtin_bit_cast(float, (u32)((u32)u << 16)); }
__device__ __forceinline__ float b2f_lo(u32 p){ return __builtin_bit_cast(float, p << 16); }
__device__ __forceinline__ float b2f_hi(u32 p){ return __builtin_bit_cast(float, p & 0xffff0000u); }
__device__ __forceinline__ u32 f2b_bits(float f){ u32 u = __builtin_bit_cast(u32, f); return (u + 0x7fffu + ((u >> 16) & 1u)) >> 16; }
__device__ __forceinline__ u16 f2b(float f){ return (u16)f2b_bits(f); }
__device__ __forceinline__ u32 packb(float lo, float hi){ return f2b_bits(lo) | (f2b_bits(hi) << 16); }

typedef __bf16 bf16x2 __attribute__((ext_vector_type(2)));
#if defined(__has_builtin)
#if __has_builtin(__builtin_amdgcn_fdot2_f32_bf16)
#define HAVE_DOT2_BUILTIN 1
#endif
#endif

#ifdef HAVE_DOT2_BUILTIN
__device__ __forceinline__ float dot2b(u32 a, u32 b, float c){
  return __builtin_amdgcn_fdot2_f32_bf16(__builtin_bit_cast(bf16x2, a),
                                         __builtin_bit_cast(bf16x2, b), c, false);
}
#else
__device__ __forceinline__ float dot2b(u32 a, u32 b, float c){
  c = fmaf(b2f_lo(a), b2f_lo(b), c);
  return fmaf(b2f_hi(a), b2f_hi(b), c);
}
#endif

__global__ __launch_bounds__(256) void zero_kernel(int* __restrict__ counts,
                                                   int* __restrict__ edge_ids)
{
  int i = blockIdx.x * 256 + threadIdx.x;
  if (i < NN) counts[i] = 0;
  if (i < NE) edge_ids[i] = 0;
}

// ---------------- qw = (node_attr @ Wq) @ Wdot (per head), stored bf16 [N,64]
__global__ __launch_bounds__(256) void qw_kernel(const float* __restrict__ node_attr,
                                                 const float* __restrict__ Wq,
                                                 const float* __restrict__ Wdot,
                                                 u16* __restrict__ qw)
{
  __shared__ __align__(16) u16 sWqT[64 * 128];
  __shared__ float sWdot[64];
  __shared__ u32 s_x[4][64];
  __shared__ float s_q[4][64];
  int tid = threadIdx.x;
  for (int idx = tid; idx < 128 * 64; idx += 256) { int i = idx >> 6, j = idx & 63; sWqT[j * 128 + i] = f2b(Wq[idx]); }
  for (int idx = tid; idx < 64; idx += 256) sWdot[idx] = Wdot[idx];
  __syncthreads();
  int wv = tid >> 6, lane = tid & 63;
  int n = blockIdx.x * 4 + wv;
  if (n < NN) {
    float2 x2 = ((const float2*)(node_attr + (size_t)n * 128))[lane];
    s_x[wv][lane] = packb(x2.x, x2.y);
  } else {
    s_x[wv][lane] = 0;
  }
  __syncthreads();
  const uint4* wr = (const uint4*)(sWqT + lane * 128);
  float q = 0.f;
#pragma unroll
  for (int p = 0; p < 16; ++p) {
    uint4 c = wr[p];
    q = dot2b(c.x, s_x[wv][p * 4 + 0], q);
    q = dot2b(c.y, s_x[wv][p * 4 + 1], q);
    q = dot2b(c.z, s_x[wv][p * 4 + 2], q);
    q = dot2b(c.w, s_x[wv][p * 4 + 3], q);
  }
  s_q[wv][lane] = q;
  __syncthreads();
  if (n >= NN) return;
  int r = lane & 7, base = lane & 56;
  float acc = 0.f;
#pragma unroll
  for (int i = 0; i < 8; ++i) acc += s_q[wv][base + i] * sWdot[i * 8 + r];
  qw[(size_t)n * 64 + lane] = f2b(acc);
}

// ---------------- shared conv building blocks (lane = one edge)
__device__ __forceinline__ void compute_hid(const u16* sW1T, const float* sb1,
                                            const u32* eap, u32* hidp)
{
#pragma unroll
  for (int j = 0; j < 64; j += 2) {
    const uint4* w = (const uint4*)(sW1T + j * 16);
    uint4 c0 = w[0], c1 = w[1], c2 = w[2], c3 = w[3];
    float a0 = sb1[j], a1 = sb1[j + 1];
    a0 = dot2b(c0.x, eap[0], a0); a0 = dot2b(c0.y, eap[1], a0);
    a0 = dot2b(c0.z, eap[2], a0); a0 = dot2b(c0.w, eap[3], a0);
    a0 = dot2b(c1.x, eap[4], a0); a0 = dot2b(c1.y, eap[5], a0);
    a0 = dot2b(c1.z, eap[6], a0); a0 = dot2b(c1.w, eap[7], a0);
    a1 = dot2b(c2.x, eap[0], a1); a1 = dot2b(c2.y, eap[1], a1);
    a1 = dot2b(c2.z, eap[2], a1); a1 = dot2b(c2.w, eap[3], a1);
    a1 = dot2b(c3.x, eap[4], a1); a1 = dot2b(c3.y, eap[5], a1);
    a1 = dot2b(c3.z, eap[6], a1); a1 = dot2b(c3.w, eap[7], a1);
    hidp[j >> 1] = packb(fmaxf(a0, 0.f), fmaxf(a1, 0.f));
  }
}

__device__ __forceinline__ void compute_gt(const u16* sWang, const u32* shp,
                                           const float* xrow_g, u32* tp)
{
  const float4* xrow = (const float4*)xrow_g;
#pragma unroll
  for (int i = 0; i < 128; i += 8) {
    float4 xa = xrow[i >> 2], xb = xrow[(i >> 2) + 1];
    u32 xs[4] = { packb(xa.x, xa.y), packb(xa.z, xa.w),
                  packb(xb.x, xb.y), packb(xb.z, xb.w) };
#pragma unroll
    for (int u = 0; u < 4; ++u) {
      int i2 = i + u * 2;
      const uint4* wr = (const uint4*)(sWang + i2 * 16);
      uint4 r0 = wr[0], r1 = wr[1], r2 = wr[2], r3 = wr[3];
      float g0 = 0.f, g1 = 0.f;
      g0 = dot2b(r0.x, shp[0], g0); g0 = dot2b(r0.y, shp[1], g0);
      g0 = dot2b(r0.z, shp[2], g0); g0 = dot2b(r0.w, shp[3], g0);
      g0 = dot2b(r1.x, shp[4], g0); g0 = dot2b(r1.y, shp[5], g0);
      g0 = dot2b(r1.z, shp[6], g0); g0 = dot2b(r1.w, shp[7], g0);
      g1 = dot2b(r2.x, shp[0], g1); g1 = dot2b(r2.y, shp[1], g1);
      g1 = dot2b(r2.z, shp[2], g1); g1 = dot2b(r2.w, shp[3], g1);
      g1 = dot2b(r3.x, shp[4], g1); g1 = dot2b(r3.y, shp[5], g1);
      g1 = dot2b(r3.z, shp[6], g1); g1 = dot2b(r3.w, shp[7], g1);
      tp[i2 >> 1] = packb(b2f_lo(xs[u]) * g0, b2f_hi(xs[u]) * g1);
    }
  }
}

// one output column value: (t . Wlin[:,j]) * (hid . W2[:,j])
__device__ __forceinline__ float col_val(const u16* sW2T, const u16* sWlinT,
                                         const u32* hidp, const u32* tp, int j)
{
  const uint4* w2 = (const uint4*)(sW2T + j * 64);
  float r0 = 0.f, r1 = 0.f;
#pragma unroll
  for (int q = 0; q < 8; q += 2) {
    uint4 ca = w2[q], cb = w2[q + 1];
    r0 = dot2b(ca.x, hidp[q * 4 + 0], r0); r0 = dot2b(ca.y, hidp[q * 4 + 1], r0);
    r0 = dot2b(ca.z, hidp[q * 4 + 2], r0); r0 = dot2b(ca.w, hidp[q * 4 + 3], r0);
    r1 = dot2b(cb.x, hidp[q * 4 + 4], r1); r1 = dot2b(cb.y, hidp[q * 4 + 5], r1);
    r1 = dot2b(cb.z, hidp[q * 4 + 6], r1); r1 = dot2b(cb.w, hidp[q * 4 + 7], r1);
  }
  const uint4* wl = (const uint4*)(sWlinT + j * 128);
  float a0 = 0.f, a1 = 0.f;
#pragma unroll
  for (int q = 0; q < 16; q += 2) {
    uint4 ca = wl[q], cb = wl[q + 1];
    a0 = dot2b(ca.x, tp[q * 4 + 0], a0); a0 = dot2b(ca.y, tp[q * 4 + 1], a0);
    a0 = dot2b(ca.z, tp[q * 4 + 2], a0); a0 = dot2b(ca.w, tp[q * 4 + 3], a0);
    a1 = dot2b(cb.x, tp[q * 4 + 4], a1); a1 = dot2b(cb.y, tp[q * 4 + 5], a1);
    a1 = dot2b(cb.z, tp[q * 4 + 6], a1); a1 = dot2b(cb.w, tp[q * 4 + 7], a1);
  }
  return (a0 + a1) * (r0 + r1);
}

// load fp32 edge rows, convert to packed bf16
__device__ __forceinline__ void load_edge_vecs(const float* edge_attr, const float* edge_sh,
                                               int e, u32* eap, u32* shp)
{
  const float4* pa = (const float4*)(edge_attr + (size_t)e * 16);
  float4 a0 = pa[0], a1 = pa[1], a2 = pa[2], a3 = pa[3];
  eap[0] = packb(a0.x, a0.y); eap[1] = packb(a0.z, a0.w);
  eap[2] = packb(a1.x, a1.y); eap[3] = packb(a1.z, a1.w);
  eap[4] = packb(a2.x, a2.y); eap[5] = packb(a2.z, a2.w);
  eap[6] = packb(a3.x, a3.y); eap[7] = packb(a3.z, a3.w);
  const float4* ps = (const float4*)(edge_sh + (size_t)e * 16);
  float4 s0 = ps[0], s1 = ps[1], s2 = ps[2], s3 = ps[3];
  shp[0] = packb(s0.x, s0.y); shp[1] = packb(s0.z, s0.w);
  shp[2] = packb(s1.x, s1.y); shp[3] = packb(s1.z, s1.w);
  shp[4] = packb(s2.x, s2.y); shp[5] = packb(s2.z, s2.w);
  shp[6] = packb(s3.x, s3.y); shp[7] = packb(s3.z, s3.w);
}

// ---------------- conv_k fused with alpha: alpha[E,8] = per-head dot(qw[dst], k_e)
__global__ __launch_bounds__(256, 2) void conv_k_alpha_kernel(
    const float* __restrict__ node_attr, const float* __restrict__ edge_attr,
    const float* __restrict__ edge_sh, const int* __restrict__ edge_index,
    const float* __restrict__ W1, const float* __restrict__ b1,
    const float* __restrict__ W2, const float* __restrict__ Wang,
    const float* __restrict__ Wlin, const u16* __restrict__ qw,
    float* __restrict__ alpha)
{
  __shared__ __align__(16) u16 sW1T[64 * 16];
  __shared__ float sb1[64];
  __shared__ __align__(16) u16 sW2T[64 * 64];
  __shared__ __align__(16) u16 sWang[128 * 16];
  __shared__ __align__(16) u16 sWlinT[64 * 128];
  int tid = threadIdx.x;
  for (int idx = tid; idx < 16 * 64; idx += 256) { int i = idx >> 6, j = idx & 63; sW1T[j * 16 + i] = f2b(W1[idx]); }
  for (int idx = tid; idx < 64; idx += 256) sb1[idx] = b1[idx];
  for (int idx = tid; idx < 64 * 64; idx += 256) { int i = idx >> 6, j = idx & 63; sW2T[j * 64 + i] = f2b(W2[idx]); }
  for (int idx = tid; idx < 128 * 16; idx += 256) sWang[idx] = f2b(Wang[idx]);
  for (int idx = tid; idx < 128 * 64; idx += 256) { int i = idx >> 6, j = idx & 63; sWlinT[j * 128 + i] = f2b(Wlin[idx]); }
  __syncthreads();
  int e = blockIdx.x * 256 + tid;
  if (e >= NE) return;
  int src = edge_index[e];          if ((u32)src >= NN) src = 0;
  int dst = edge_index[NE + e];     if ((u32)dst >= NN) dst = 0;
  u32 qwp[32];
  { const uint4* qp = (const uint4*)(qw + (size_t)dst * 64);
#pragma unroll
    for (int i = 0; i < 8; ++i) { uint4 v = qp[i]; qwp[i*4] = v.x; qwp[i*4+1] = v.y; qwp[i*4+2] = v.z; qwp[i*4+3] = v.w; } }
  u32 eap[8], shp[8];
  load_edge_vecs(edge_attr, edge_sh, e, eap, shp);
  u32 hidp[32], tp[64];
  compute_hid(sW1T, sb1, eap, hidp);
  compute_gt(sWang, shp, node_attr + (size_t)src * 128, tp);
  float ah[8] = {0.f,0.f,0.f,0.f,0.f,0.f,0.f,0.f};
  for (int j2 = 0; j2 < 32; ++j2) {
    float v0 = col_val(sW2T, sWlinT, hidp, tp, 2 * j2);
    float v1 = col_val(sW2T, sWlinT, hidp, tp, 2 * j2 + 1);
    ah[j2 >> 2] = dot2b(qwp[j2], packb(v0, v1), ah[j2 >> 2]);
  }
  float4* ap = (float4*)(alpha + (size_t)e * 8);
  ap[0] = make_float4(ah[0], ah[1], ah[2], ah[3]);
  ap[1] = make_float4(ah[4], ah[5], ah[6], ah[7]);
}

// ---------------- conv_v: v_e[E,128] bf16
__global__ __launch_bounds__(256, 2) void conv_v_kernel(
    const float* __restrict__ node_attr, const float* __restrict__ edge_attr,
    const float* __restrict__ edge_sh, const int* __restrict__ edge_index,
    const float* __restrict__ W1, const float* __restrict__ b1,
    const float* __restrict__ W2, const float* __restrict__ Wang,
    const float* __restrict__ Wlin, u16* __restrict__ v_out)
{
  __shared__ __align__(16) u16 sW1T[64 * 16];
  __shared__ float sb1[64];
  __shared__ __align__(16) u16 sW2T[128 * 64];
  __shared__ __align__(16) u16 sWang[128 * 16];
  __shared__ __align__(16) u16 sWlinT[128 * 128];
  int tid = threadIdx.x;
  for (int idx = tid; idx < 16 * 64; idx += 256) { int i = idx >> 6, j = idx & 63; sW1T[j * 16 + i] = f2b(W1[idx]); }
  for (int idx = tid; idx < 64; idx += 256) sb1[idx] = b1[idx];
  for (int idx = tid; idx < 64 * 128; idx += 256) { int i = idx >> 7, j = idx & 127; sW2T[j * 64 + i] = f2b(W2[idx]); }
  for (int idx = tid; idx < 128 * 16; idx += 256) sWang[idx] = f2b(Wang[idx]);
  for (int idx = tid; idx < 128 * 128; idx += 256) { int i = idx >> 7, j = idx & 127; sWlinT[j * 128 + i] = f2b(Wlin[idx]); }
  __syncthreads();
  int e = blockIdx.x * 256 + tid;
  if (e >= NE) return;
  int src = edge_index[e];  if ((u32)src >= NN) src = 0;
  u32 eap[8], shp[8];
  load_edge_vecs(edge_attr, edge_sh, e, eap, shp);
  u32 hidp[32], tp[64];
  compute_hid(sW1T, sb1, eap, hidp);
  compute_gt(sWang, shp, node_attr + (size_t)src * 128, tp);
  u16* dst_g = v_out + (size_t)e * 128;
  for (int j8 = 0; j8 < 128; j8 += 8) {
    u32 buf[4];
#pragma unroll
    for (int jj = 0; jj < 8; jj += 2) {
      float v0 = col_val(sW2T, sWlinT, hidp, tp, j8 + jj);
      float v1 = col_val(sW2T, sWlinT, hidp, tp, j8 + jj + 1);
      buf[jj >> 1] = packb(v0, v1);
    }
    ((uint4*)dst_g)[j8 >> 3] = make_uint4(buf[0], buf[1], buf[2], buf[3]);
  }
}

// ---------------- CSR build
__global__ __launch_bounds__(256) void count_kernel(const int* __restrict__ edge_index,
                                                    int* __restrict__ counts)
{
  int e = blockIdx.x * 256 + threadIdx.x;
  if (e < NE) { int d = edge_index[NE + e]; if ((u32)d >= NN) d = 0; atomicAdd(&counts[d], 1); }
}

__global__ __launch_bounds__(1024) void scan_kernel(const int* __restrict__ counts,
                                                    int* __restrict__ row_ptr,
                                                    int* __restrict__ cursor)
{
  __shared__ int s[1024];
  int tid = threadIdx.x;
  int base = tid * STRIP;
  int sum = 0;
  for (int i = 0; i < STRIP; ++i) { int idx = base + i; sum += (idx < NN) ? counts[idx] : 0; }
  s[tid] = sum;
  __syncthreads();
  for (int off = 1; off < 1024; off <<= 1) {
    int v = s[tid];
    int add = (tid >= off) ? s[tid - off] : 0;
    __syncthreads();
    s[tid] = v + add;
    __syncthreads();
  }
  int running = (tid == 0) ? 0 : s[tid - 1];
  for (int i = 0; i < STRIP; ++i) {
    int idx = base + i;
    if (idx < NN) { row_ptr[idx] = running; cursor[idx] = running; running += counts[idx]; }
  }
  if (tid == 1023) row_ptr[NN] = running;
}

__global__ __launch_bounds__(256) void fill_kernel(const int* __restrict__ edge_index,
                                                   int* __restrict__ cursor,
                                                   int* __restrict__ edge_ids)
{
  int e = blockIdx.x * 256 + threadIdx.x;
  if (e < NE) {
    int dst = edge_index[NE + e]; if ((u32)dst >= NN) dst = 0;
    int pos = atomicAdd(&cursor[dst], 1);
    if ((u32)pos < NE) edge_ids[pos] = e;
  }
}

// ---------------- per-node: softmax over incoming edges, gather v, @ Wout (fp32 out)
__global__ __launch_bounds__(128) void out_kernel(const int* __restrict__ row_ptr,
                                                  const int* __restrict__ edge_ids,
                                                  const float* __restrict__ alpha,
                                                  const u16* __restrict__ v_e,
                                                  const float* __restrict__ Wout,
                                                  float* __restrict__ out)
{
  int n = blockIdx.x, tid = threadIdx.x;
  __shared__ float s_red[128];
  __shared__ float s_amax[8], s_dinv[8];
  __shared__ float s_acc[128];
  int beg = row_ptr[n], end = row_ptr[n + 1];
  if (beg < 0) beg = 0; if (beg > NE) beg = NE;
  if (end < beg) end = beg; if (end > NE) end = NE;
  int deg = end - beg;
  int h = tid & 7, slot = tid >> 3;
  float m = -3.0e38f;
  for (int j = slot; j < deg; j += 16) {
    int e = edge_ids[beg + j]; if ((u32)e >= NE) e = 0;
    m = fmaxf(m, alpha[(size_t)e * 8 + h]);
  }
  s_red[tid] = m; __syncthreads();
  for (int s = 64; s >= 8; s >>= 1) { if (tid < s) s_red[tid] = fmaxf(s_red[tid], s_red[tid + s]); __syncthreads(); }
  if (tid < 8) s_amax[tid] = s_red[tid];
  __syncthreads();
  float dsum = 0.f;
  for (int j = slot; j < deg; j += 16) {
    int e = edge_ids[beg + j]; if ((u32)e >= NE) e = 0;
    dsum += __expf(alpha[(size_t)e * 8 + h] - s_amax[h]);
  }
  s_red[tid] = dsum; __syncthreads();
  for (int s = 64; s >= 8; s >>= 1) { if (tid < s) s_red[tid] += s_red[tid + s]; __syncthreads(); }
  if (tid < 8) s_dinv[tid] = 1.f / s_red[tid];
  __syncthreads();
  int hh = tid >> 4;
  float amax_hh = s_amax[hh], dinv_hh = s_dinv[hh];
  float acc = 0.f;
  for (int j = 0; j < deg; ++j) {
    int e = edge_ids[beg + j]; if ((u32)e >= NE) e = 0;
    float attn = __expf(alpha[(size_t)e * 8 + hh] - amax_hh) * dinv_hh;
    acc += attn * b2f(v_e[(size_t)e * 128 + tid]);
  }
  s_acc[tid] = acc; __syncthreads();
  float y = 0.f;
  for (int i = 0; i < 128; ++i) y += s_acc[i] * Wout[i * 128 + tid];
  out[(size_t)n * 128 + tid] = y;
}

extern "C" void kernel_launch(void* const* d_in, const int* in_sizes, int n_in,
                              void* d_out, int out_size, void* d_ws, size_t ws_size,
                              hipStream_t stream)
{
  const float* node_attr = (const float*)d_in[0];
  const float* edge_attr = (const float*)d_in[1];
  const float* edge_sh   = (const float*)d_in[2];
  const float* Wq        = (const float*)d_in[3];
  const float* Wang_k    = (const float*)d_in[4];
  const float* Wlin_k    = (const float*)d_in[5];
  const float* W1k       = (const float*)d_in[6];
  const float* b1k       = (const float*)d_in[7];
  const float* W2k       = (const float*)d_in[8];
  const float* Wang_v    = (const float*)d_in[9];
  const float* Wlin_v    = (const float*)d_in[10];
  const float* W1v       = (const float*)d_in[11];
  const float* b1v       = (const float*)d_in[12];
  const float* W2v       = (const float*)d_in[13];
  const float* Wdot      = (const float*)d_in[14];
  const float* Wout      = (const float*)d_in[15];
  const int* edge_index  = (const int*)d_in[16];
  float* out = (float*)d_out;

  char* ws = (char*)d_ws;
  u16*   v_e      = (u16*)(ws + 0);                 // E*128*2  = 204,800,000
  float* alpha    = (float*)(ws + 204800000);       // E*8*4    =  25,600,000
  u16*   qw       = (u16*)(ws + 230400000);         // N*64*2   =   6,400,000
  int*   counts   = (int*)(ws + 236800000);         // 200,064
  int*   row_ptr  = (int*)(ws + 237000064);         // 200,064
  int*   cursor   = (int*)(ws + 237200128);         // 200,064
  int*   edge_ids = (int*)(ws + 237400192);         // 3,200,000 -> total 240,600,192

  zero_kernel<<<dim3((NE + 255) / 256), dim3(256), 0, stream>>>(counts, edge_ids);
  qw_kernel<<<dim3((NN + 3) / 4), dim3(256), 0, stream>>>(node_attr, Wq, Wdot, qw);
  conv_v_kernel<<<dim3((NE + 255) / 256), dim3(256), 0, stream>>>(
      node_attr, edge_attr, edge_sh, edge_index, W1v, b1v, W2v, Wang_v, Wlin_v, v_e);
  conv_k_alpha_kernel<<<dim3((NE + 255) / 256), dim3(256), 0, stream>>>(
      node_attr, edge_attr, edge_sh, edge_index, W1k, b1k, W2k, Wang_k, Wlin_k, qw, alpha);
  count_kernel<<<dim3((NE + 255) / 256), dim3(256), 0, stream>>>(edge_index, counts);
  scan_kernel<<<dim3(1), dim3(1024), 0, stream>>>(counts, row_ptr, cursor);
  fill_kernel<<<dim3((NE + 255) / 256), dim3(256), 0, stream>>>(edge_index, cursor, edge_ids);
  out_kernel<<<dim3(NN), dim3(128), 0, stream>>>(row_ptr, edge_ids, alpha, v_e, Wout, out);
}

// Round 5
// 1332.020 us; speedup vs baseline: 1.3988x; 1.3988x over previous
//
#include <hip/hip_runtime.h>
#include <stdint.h>

#define NN 50000
#define NE 800000
#define STRIP 49   // ceil(NN/1024)

typedef unsigned int u32;
typedef uint16_t u16;

__device__ __forceinline__ float b2f(u16 u){ return __builtin_bit_cast(float, (u32)((u32)u << 16)); }
__device__ __forceinline__ float b2f_lo(u32 p){ return __builtin_bit_cast(float, p << 16); }
__device__ __forceinline__ float b2f_hi(u32 p){ return __builtin_bit_cast(float, p & 0xffff0000u); }
__device__ __forceinline__ u32 f2b_bits(float f){ u32 u = __builtin_bit_cast(u32, f); return (u + 0x7fffu + ((u >> 16) & 1u)) >> 16; }
__device__ __forceinline__ u16 f2b(float f){ return (u16)f2b_bits(f); }
__device__ __forceinline__ u32 packb(float lo, float hi){ return f2b_bits(lo) | (f2b_bits(hi) << 16); }

typedef __bf16 bf16x2 __attribute__((ext_vector_type(2)));
#if defined(__has_builtin)
#if __has_builtin(__builtin_amdgcn_fdot2_f32_bf16)
#define HAVE_DOT2_BUILTIN 1
#endif
#endif

#ifdef HAVE_DOT2_BUILTIN
__device__ __forceinline__ float dot2b(u32 a, u32 b, float c){
  return __builtin_amdgcn_fdot2_f32_bf16(__builtin_bit_cast(bf16x2, a),
                                         __builtin_bit_cast(bf16x2, b), c, false);
}
#else
__device__ __forceinline__ float dot2b(u32 a, u32 b, float c){
  c = fmaf(b2f_lo(a), b2f_lo(b), c);
  return fmaf(b2f_hi(a), b2f_hi(b), c);
}
#endif

// ---- MFMA plumbing (guide-verified layouts) ----
typedef __attribute__((ext_vector_type(8))) short short8;
typedef __attribute__((ext_vector_type(4))) float f32x4;
__device__ __forceinline__ f32x4 mf32(uint4 a, uint4 b, f32x4 c){
  return __builtin_amdgcn_mfma_f32_16x16x32_bf16(
      __builtin_bit_cast(short8, a), __builtin_bit_cast(short8, b), c, 0, 0, 0);
}

// pre-transposed weight layout offsets in u16 units (padded, zero-filled)
#define OFF_WANG_V 0        // [128][40]
#define OFF_W1_V   5120     // [64][40]
#define OFF_WLIN_V 7680     // [128][136]
#define OFF_W2_V   25088    // [128][72]
#define OFF_WANG_K 34304    // [128][40]
#define OFF_W1_K   39424    // [64][40]
#define OFF_WLIN_K 41984    // [64][136]
#define OFF_W2_K   50688    // [64][72]
#define WT_TOTAL   55296

__global__ __launch_bounds__(256) void zero_kernel(int* __restrict__ counts,
                                                   int* __restrict__ edge_ids)
{
  int i = blockIdx.x * 256 + threadIdx.x;
  if (i < NN) counts[i] = 0;
  if (i < NE) edge_ids[i] = 0;
}

// ---------------- one-time weight transpose/pad/bf16 prep
__global__ __launch_bounds__(256) void prep_w_kernel(
    const float* __restrict__ Wang_v, const float* __restrict__ W1_v,
    const float* __restrict__ Wlin_v, const float* __restrict__ W2_v,
    const float* __restrict__ Wang_k, const float* __restrict__ W1_k,
    const float* __restrict__ Wlin_k, const float* __restrict__ W2_k,
    u16* __restrict__ wt)
{
  int idx = blockIdx.x * 256 + threadIdx.x;
  if (idx >= WT_TOTAL) return;
  float val = 0.f;
  if (idx < OFF_W1_V) {                      // WangT_v: B^T[n][k] = Wang[n*16+k]
    int l = idx - OFF_WANG_V, n = l / 40, k = l % 40;
    if (k < 16) val = Wang_v[n * 16 + k];
  } else if (idx < OFF_WLIN_V) {             // W1T_v: B^T[n][k] = W1[k*64+n]
    int l = idx - OFF_W1_V, n = l / 40, k = l % 40;
    if (k < 16) val = W1_v[k * 64 + n];
  } else if (idx < OFF_W2_V) {               // WlinT_v: B^T[n][k] = Wlin[k*128+n]
    int l = idx - OFF_WLIN_V, n = l / 136, k = l % 136;
    if (k < 128) val = Wlin_v[k * 128 + n];
  } else if (idx < OFF_WANG_K) {             // W2T_v: B^T[n][k] = W2[k*128+n]
    int l = idx - OFF_W2_V, n = l / 72, k = l % 72;
    if (k < 64) val = W2_v[k * 128 + n];
  } else if (idx < OFF_W1_K) {
    int l = idx - OFF_WANG_K, n = l / 40, k = l % 40;
    if (k < 16) val = Wang_k[n * 16 + k];
  } else if (idx < OFF_WLIN_K) {
    int l = idx - OFF_W1_K, n = l / 40, k = l % 40;
    if (k < 16) val = W1_k[k * 64 + n];
  } else if (idx < OFF_W2_K) {               // WlinT_k: [64][136], src [128][64]
    int l = idx - OFF_WLIN_K, n = l / 136, k = l % 136;
    if (k < 128) val = Wlin_k[k * 64 + n];
  } else {                                   // W2T_k: [64][72], src [64][64]
    int l = idx - OFF_W2_K, n = l / 72, k = l % 72;
    if (k < 64) val = W2_k[k * 64 + n];
  }
  wt[idx] = f2b(val);
}

// ---------------- qw = (node_attr @ Wq) @ Wdot (per head), stored bf16 [N,64]
__global__ __launch_bounds__(256) void qw_kernel(const float* __restrict__ node_attr,
                                                 const float* __restrict__ Wq,
                                                 const float* __restrict__ Wdot,
                                                 u16* __restrict__ qw)
{
  __shared__ __align__(16) u16 sWqT[64 * 128];
  __shared__ float sWdot[64];
  __shared__ u32 s_x[4][64];
  __shared__ float s_q[4][64];
  int tid = threadIdx.x;
  for (int idx = tid; idx < 128 * 64; idx += 256) { int i = idx >> 6, j = idx & 63; sWqT[j * 128 + i] = f2b(Wq[idx]); }
  for (int idx = tid; idx < 64; idx += 256) sWdot[idx] = Wdot[idx];
  __syncthreads();
  int wv = tid >> 6, lane = tid & 63;
  int n = blockIdx.x * 4 + wv;
  if (n < NN) {
    float2 x2 = ((const float2*)(node_attr + (size_t)n * 128))[lane];
    s_x[wv][lane] = packb(x2.x, x2.y);
  } else {
    s_x[wv][lane] = 0;
  }
  __syncthreads();
  const uint4* wr = (const uint4*)(sWqT + lane * 128);
  float q = 0.f;
#pragma unroll
  for (int p = 0; p < 16; ++p) {
    uint4 c = wr[p];
    q = dot2b(c.x, s_x[wv][p * 4 + 0], q);
    q = dot2b(c.y, s_x[wv][p * 4 + 1], q);
    q = dot2b(c.z, s_x[wv][p * 4 + 2], q);
    q = dot2b(c.w, s_x[wv][p * 4 + 3], q);
  }
  s_q[wv][lane] = q;
  __syncthreads();
  if (n >= NN) return;
  int r = lane & 7, base = lane & 56;
  float acc = 0.f;
#pragma unroll
  for (int i = 0; i < 8; ++i) acc += s_q[wv][base + i] * sWdot[i * 8 + r];
  qw[(size_t)n * 64 + lane] = f2b(acc);
}

// ---------------- fused MFMA conv (v and k paths) + alpha
// block = 256 threads (4 waves) = 64 edges. NE = 64*12500 exactly.
__global__ __launch_bounds__(256, 2) void conv_fused_kernel(
    const float* __restrict__ node_attr, const float* __restrict__ edge_attr,
    const float* __restrict__ edge_sh, const int* __restrict__ edge_index,
    const float* __restrict__ b1v, const float* __restrict__ b1k,
    const u16* __restrict__ wt, const u16* __restrict__ qw,
    u16* __restrict__ v_out, float* __restrict__ alpha)
{
  // sW: phase-multiplexed weights/staging (34816 B)
  // sT: t tile [64][136] bf16 (17408 B), also C buffer
  // sH: hid tile [64][72] bf16 (9216 B)
  __shared__ __align__(16) u16 sW[17408];
  __shared__ __align__(16) u16 sT[64 * 136];
  __shared__ __align__(16) u16 sH[64 * 72];
  uint4* sW4 = (uint4*)sW;
  uint4* sT4 = (uint4*)sT;
  uint4* sH4 = (uint4*)sH;
  u32* sW32 = (u32*)sW;

  const int tid = threadIdx.x;
  const int wv = tid >> 6, lane = tid & 63, lq = lane >> 4, ln = lane & 15;
  const int e0 = blockIdx.x * 64;

  // ---- helpers as lambdas ----
  auto stage_easha = [&](){
    // EA -> sW u16[0..2560) rows [64][40]; SH -> u16[2560..5120)
    int r = tid >> 2, kq = tid & 3;
    {
      float4 ea = ((const float4*)(edge_attr + (size_t)(e0 + r) * 16))[kq];
      sW32[r * 20 + kq * 2]     = packb(ea.x, ea.y);
      sW32[r * 20 + kq * 2 + 1] = packb(ea.z, ea.w);
      sW32[r * 20 + 8 + kq]  = 0;   // zero k in [16,24)
      sW32[r * 20 + 12 + kq] = 0;   // zero k in [24,32)
    }
    {
      float4 sh = ((const float4*)(edge_sh + (size_t)(e0 + r) * 16))[kq];
      int b = 1280;
      sW32[b + r * 20 + kq * 2]     = packb(sh.x, sh.y);
      sW32[b + r * 20 + kq * 2 + 1] = packb(sh.z, sh.w);
      sW32[b + r * 20 + 8 + kq]  = 0;
      sW32[b + r * 20 + 12 + kq] = 0;
    }
  };
  auto copy_w = [&](int dst4, int src_u16, int n4){
    const uint4* g4 = (const uint4*)(wt + src_u16);
    for (int i = tid; i < n4; i += 256) sW4[dst4 + i] = g4[i];
  };

  int srcs[4][4];
  float xf[2][4][4];
  auto load_x = [&](){
#pragma unroll
    for (int et = 0; et < 4; ++et)
#pragma unroll
      for (int r = 0; r < 4; ++r) {
        int s = edge_index[e0 + et * 16 + lq * 4 + r];
        if ((u32)s >= NN) s = 0;
        srcs[et][r] = s;
      }
#pragma unroll
    for (int c = 0; c < 2; ++c) {
      int col = (wv + 4 * c) * 16 + ln;
#pragma unroll
      for (int et = 0; et < 4; ++et)
#pragma unroll
        for (int r = 0; r < 4; ++r)
          xf[c][et][r] = node_attr[(size_t)srcs[et][r] * 128 + col];
    }
  };

  auto phase1 = [&](const float* b1){
    float bias = b1[wv * 16 + ln];
    // hid = relu(EA @ W1 + b1): EA at sW4 row*5, W1T at sW4 640 + n*5
#pragma unroll
    for (int et = 0; et < 4; ++et) {
      uint4 a = sW4[(et * 16 + ln) * 5 + lq];
      uint4 b = sW4[640 + (wv * 16 + ln) * 5 + lq];
      f32x4 c = {0.f, 0.f, 0.f, 0.f};
      c = mf32(a, b, c);
#pragma unroll
      for (int r = 0; r < 4; ++r)
        sH[(et * 16 + lq * 4 + r) * 72 + wv * 16 + ln] = f2b(fmaxf(c[r] + bias, 0.f));
    }
    // t = (SH @ WangT) * x : SH at sW4 320 + row*5, WangT at sW4 960 + n*5
#pragma unroll
    for (int c2 = 0; c2 < 2; ++c2) {
      int ct = wv + 4 * c2;
#pragma unroll
      for (int et = 0; et < 4; ++et) {
        uint4 a = sW4[320 + (et * 16 + ln) * 5 + lq];
        uint4 b = sW4[960 + (ct * 16 + ln) * 5 + lq];
        f32x4 c = {0.f, 0.f, 0.f, 0.f};
        c = mf32(a, b, c);
#pragma unroll
        for (int r = 0; r < 4; ++r)
          sT[(et * 16 + lq * 4 + r) * 136 + ct * 16 + ln] = f2b(c[r] * xf[c2][et][r]);
      }
    }
  };

  f32x4 acc1[2][4];
  auto phase2a = [&](int ncol){
#pragma unroll
    for (int c2 = 0; c2 < 2; ++c2) {
      if (c2 >= ncol) break;
      int ct = (ncol == 2) ? (wv + 4 * c2) : wv;
#pragma unroll
      for (int et = 0; et < 4; ++et) {
        f32x4 acc = {0.f, 0.f, 0.f, 0.f};
#pragma unroll
        for (int ks = 0; ks < 4; ++ks) {
          uint4 a = sT4[(et * 16 + ln) * 17 + ks * 4 + lq];
          uint4 b = sW4[(ct * 16 + ln) * 17 + ks * 4 + lq];
          acc = mf32(a, b, acc);
        }
        acc1[c2][et] = acc;
      }
    }
  };

  // ================= V path =================
  load_x();
  stage_easha();
  copy_w(640, OFF_W1_V, 320);
  copy_w(960, OFF_WANG_V, 640);
  __syncthreads();
  phase1(b1v);
  __syncthreads();
  copy_w(0, OFF_WLIN_V, 2176);
  __syncthreads();
  phase2a(2);
  __syncthreads();
  copy_w(0, OFF_W2_V, 1152);
  __syncthreads();
  // phase2b_v: acc2 = hid @ W2, C = acc1*acc2 -> sT (t consumed)
#pragma unroll
  for (int c2 = 0; c2 < 2; ++c2) {
    int ct = wv + 4 * c2;
#pragma unroll
    for (int et = 0; et < 4; ++et) {
      f32x4 acc = {0.f, 0.f, 0.f, 0.f};
#pragma unroll
      for (int ks = 0; ks < 2; ++ks) {
        uint4 a = sH4[(et * 16 + ln) * 9 + ks * 4 + lq];
        uint4 b = sW4[(ct * 16 + ln) * 9 + ks * 4 + lq];
        acc = mf32(a, b, acc);
      }
#pragma unroll
      for (int r = 0; r < 4; ++r)
        sT[(et * 16 + lq * 4 + r) * 136 + ct * 16 + ln] = f2b(acc1[c2][et][r] * acc[r]);
    }
  }
  __syncthreads();
  // coalesced v store
  {
    int row = tid >> 2, seg = tid & 3;
    uint4* gp = (uint4*)(v_out + (size_t)(e0 + row) * 128);
#pragma unroll
    for (int i = 0; i < 4; ++i) gp[seg * 4 + i] = sT4[row * 17 + seg * 4 + i];
  }
  // ================= K path =================
  // stage phase1_k (sW free after phase2b_v reads; sT free after store needs sync)
  __syncthreads();
  stage_easha();
  copy_w(640, OFF_W1_K, 320);
  copy_w(960, OFF_WANG_K, 640);
  __syncthreads();
  phase1(b1k);
  __syncthreads();
  copy_w(0, OFF_WLIN_K, 1088);
  __syncthreads();
  phase2a(1);
  __syncthreads();
  copy_w(0, OFF_W2_K, 576);
  __syncthreads();
  // phase2b_k: C_k [64][72] -> sT (pitch 72)
  {
    int ct = wv;
#pragma unroll
    for (int et = 0; et < 4; ++et) {
      f32x4 acc = {0.f, 0.f, 0.f, 0.f};
#pragma unroll
      for (int ks = 0; ks < 2; ++ks) {
        uint4 a = sH4[(et * 16 + ln) * 9 + ks * 4 + lq];
        uint4 b = sW4[(ct * 16 + ln) * 9 + ks * 4 + lq];
        acc = mf32(a, b, acc);
      }
#pragma unroll
      for (int r = 0; r < 4; ++r)
        sT[(et * 16 + lq * 4 + r) * 72 + ct * 16 + ln] = f2b(acc1[0][et][r] * acc[r]);
    }
  }
  __syncthreads();
  // alpha epilogue: thread -> (edge el, quarter p handles heads 2p,2p+1)
  {
    int el = tid >> 2, p = tid & 3;
    int dst = edge_index[NE + e0 + el];
    if ((u32)dst >= NN) dst = 0;
    uint4 k0 = sT4[el * 9 + p * 2];
    uint4 k1 = sT4[el * 9 + p * 2 + 1];
    const uint4* qp = (const uint4*)(qw + (size_t)dst * 64 + p * 16);
    uint4 q0 = qp[0], q1 = qp[1];
    float a0 = 0.f, a1 = 0.f;
    a0 = dot2b(q0.x, k0.x, a0); a0 = dot2b(q0.y, k0.y, a0);
    a0 = dot2b(q0.z, k0.z, a0); a0 = dot2b(q0.w, k0.w, a0);
    a1 = dot2b(q1.x, k1.x, a1); a1 = dot2b(q1.y, k1.y, a1);
    a1 = dot2b(q1.z, k1.z, a1); a1 = dot2b(q1.w, k1.w, a1);
    ((float2*)(alpha + (size_t)(e0 + el) * 8))[p] = make_float2(a0, a1);
  }
}

// ---------------- CSR build
__global__ __launch_bounds__(256) void count_kernel(const int* __restrict__ edge_index,
                                                    int* __restrict__ counts)
{
  int e = blockIdx.x * 256 + threadIdx.x;
  if (e < NE) { int d = edge_index[NE + e]; if ((u32)d >= NN) d = 0; atomicAdd(&counts[d], 1); }
}

__global__ __launch_bounds__(1024) void scan_kernel(const int* __restrict__ counts,
                                                    int* __restrict__ row_ptr,
                                                    int* __restrict__ cursor)
{
  __shared__ int s[1024];
  int tid = threadIdx.x;
  int base = tid * STRIP;
  int sum = 0;
  for (int i = 0; i < STRIP; ++i) { int idx = base + i; sum += (idx < NN) ? counts[idx] : 0; }
  s[tid] = sum;
  __syncthreads();
  for (int off = 1; off < 1024; off <<= 1) {
    int v = s[tid];
    int add = (tid >= off) ? s[tid - off] : 0;
    __syncthreads();
    s[tid] = v + add;
    __syncthreads();
  }
  int running = (tid == 0) ? 0 : s[tid - 1];
  for (int i = 0; i < STRIP; ++i) {
    int idx = base + i;
    if (idx < NN) { row_ptr[idx] = running; cursor[idx] = running; running += counts[idx]; }
  }
  if (tid == 1023) row_ptr[NN] = running;
}

__global__ __launch_bounds__(256) void fill_kernel(const int* __restrict__ edge_index,
                                                   int* __restrict__ cursor,
                                                   int* __restrict__ edge_ids)
{
  int e = blockIdx.x * 256 + threadIdx.x;
  if (e < NE) {
    int dst = edge_index[NE + e]; if ((u32)dst >= NN) dst = 0;
    int pos = atomicAdd(&cursor[dst], 1);
    if ((u32)pos < NE) edge_ids[pos] = e;
  }
}

// ---------------- per-node softmax + weighted V gather + @Wout (fp32 out)
__global__ __launch_bounds__(128) void out_kernel(const int* __restrict__ row_ptr,
                                                  const int* __restrict__ edge_ids,
                                                  const float* __restrict__ alpha,
                                                  const u16* __restrict__ v_e,
                                                  const float* __restrict__ Wout,
                                                  float* __restrict__ out)
{
  int n = blockIdx.x, tid = threadIdx.x;
  __shared__ float s_red[128];
  __shared__ float s_amax[8], s_dinv[8];
  __shared__ float s_acc[128];
  int beg = row_ptr[n], end = row_ptr[n + 1];
  if (beg < 0) beg = 0; if (beg > NE) beg = NE;
  if (end < beg) end = beg; if (end > NE) end = NE;
  int deg = end - beg;
  int h = tid & 7, slot = tid >> 3;
  float m = -3.0e38f;
  for (int j = slot; j < deg; j += 16) {
    int e = edge_ids[beg + j]; if ((u32)e >= NE) e = 0;
    m = fmaxf(m, alpha[(size_t)e * 8 + h]);
  }
  s_red[tid] = m; __syncthreads();
  for (int s = 64; s >= 8; s >>= 1) { if (tid < s) s_red[tid] = fmaxf(s_red[tid], s_red[tid + s]); __syncthreads(); }
  if (tid < 8) s_amax[tid] = s_red[tid];
  __syncthreads();
  float dsum = 0.f;
  for (int j = slot; j < deg; j += 16) {
    int e = edge_ids[beg + j]; if ((u32)e >= NE) e = 0;
    dsum += __expf(alpha[(size_t)e * 8 + h] - s_amax[h]);
  }
  s_red[tid] = dsum; __syncthreads();
  for (int s = 64; s >= 8; s >>= 1) { if (tid < s) s_red[tid] += s_red[tid + s]; __syncthreads(); }
  if (tid < 8) s_dinv[tid] = 1.f / s_red[tid];
  __syncthreads();
  int hh = tid >> 4;
  float amax_hh = s_amax[hh], dinv_hh = s_dinv[hh];
  float acc = 0.f;
  for (int j = 0; j < deg; ++j) {
    int e = edge_ids[beg + j]; if ((u32)e >= NE) e = 0;
    float attn = __expf(alpha[(size_t)e * 8 + hh] - amax_hh) * dinv_hh;
    acc += attn * b2f(v_e[(size_t)e * 128 + tid]);
  }
  s_acc[tid] = acc; __syncthreads();
  float y = 0.f;
  for (int i = 0; i < 128; ++i) y += s_acc[i] * Wout[i * 128 + tid];
  out[(size_t)n * 128 + tid] = y;
}

extern "C" void kernel_launch(void* const* d_in, const int* in_sizes, int n_in,
                              void* d_out, int out_size, void* d_ws, size_t ws_size,
                              hipStream_t stream)
{
  const float* node_attr = (const float*)d_in[0];
  const float* edge_attr = (const float*)d_in[1];
  const float* edge_sh   = (const float*)d_in[2];
  const float* Wq        = (const float*)d_in[3];
  const float* Wang_k    = (const float*)d_in[4];
  const float* Wlin_k    = (const float*)d_in[5];
  const float* W1k       = (const float*)d_in[6];
  const float* b1k       = (const float*)d_in[7];
  const float* W2k       = (const float*)d_in[8];
  const float* Wang_v    = (const float*)d_in[9];
  const float* Wlin_v    = (const float*)d_in[10];
  const float* W1v       = (const float*)d_in[11];
  const float* b1v       = (const float*)d_in[12];
  const float* W2v       = (const float*)d_in[13];
  const float* Wdot      = (const float*)d_in[14];
  const float* Wout      = (const float*)d_in[15];
  const int* edge_index  = (const int*)d_in[16];
  float* out = (float*)d_out;

  char* ws = (char*)d_ws;
  u16*   v_e      = (u16*)(ws + 0);                 // E*128*2  = 204,800,000
  float* alpha    = (float*)(ws + 204800000);       // E*8*4    =  25,600,000
  u16*   qw       = (u16*)(ws + 230400000);         // N*64*2   =   6,400,000
  int*   counts   = (int*)(ws + 236800000);         // 200,064
  int*   row_ptr  = (int*)(ws + 237000064);         // 200,064
  int*   cursor   = (int*)(ws + 237200128);         // 200,064
  int*   edge_ids = (int*)(ws + 237400192);         // 3,200,000
  u16*   wt       = (u16*)(ws + 240600192);         // 110,592 -> total 240,710,784

  zero_kernel<<<dim3((NE + 255) / 256), dim3(256), 0, stream>>>(counts, edge_ids);
  prep_w_kernel<<<dim3((WT_TOTAL + 255) / 256), dim3(256), 0, stream>>>(
      Wang_v, W1v, Wlin_v, W2v, Wang_k, W1k, Wlin_k, W2k, wt);
  qw_kernel<<<dim3((NN + 3) / 4), dim3(256), 0, stream>>>(node_attr, Wq, Wdot, qw);
  conv_fused_kernel<<<dim3(NE / 64), dim3(256), 0, stream>>>(
      node_attr, edge_attr, edge_sh, edge_index, b1v, b1k, wt, qw, v_e, alpha);
  count_kernel<<<dim3((NE + 255) / 256), dim3(256), 0, stream>>>(edge_index, counts);
  scan_kernel<<<dim3(1), dim3(1024), 0, stream>>>(counts, row_ptr, cursor);
  fill_kernel<<<dim3((NE + 255) / 256), dim3(256), 0, stream>>>(edge_index, cursor, edge_ids);
  out_kernel<<<dim3(NN), dim3(128), 0, stream>>>(row_ptr, edge_ids, alpha, v_e, Wout, out);
}

// Round 6
// 1112.076 us; speedup vs baseline: 1.6755x; 1.1978x over previous
//
#include <hip/hip_runtime.h>
#include <stdint.h>

#define NN 50000
#define NE 800000
#define STRIP 49   // ceil(NN/1024)
#define OUT_GRID 1563

typedef unsigned int u32;
typedef uint16_t u16;

__device__ __forceinline__ float b2f(u16 u){ return __builtin_bit_cast(float, (u32)((u32)u << 16)); }
__device__ __forceinline__ float b2f_lo(u32 p){ return __builtin_bit_cast(float, p << 16); }
__device__ __forceinline__ float b2f_hi(u32 p){ return __builtin_bit_cast(float, p & 0xffff0000u); }
__device__ __forceinline__ u32 f2b_bits(float f){ u32 u = __builtin_bit_cast(u32, f); return (u + 0x7fffu + ((u >> 16) & 1u)) >> 16; }
__device__ __forceinline__ u16 f2b(float f){ return (u16)f2b_bits(f); }
__device__ __forceinline__ u32 packb(float lo, float hi){ return f2b_bits(lo) | (f2b_bits(hi) << 16); }

typedef __bf16 bf16x2 __attribute__((ext_vector_type(2)));
#if defined(__has_builtin)
#if __has_builtin(__builtin_amdgcn_fdot2_f32_bf16)
#define HAVE_DOT2_BUILTIN 1
#endif
#endif

#ifdef HAVE_DOT2_BUILTIN
__device__ __forceinline__ float dot2b(u32 a, u32 b, float c){
  return __builtin_amdgcn_fdot2_f32_bf16(__builtin_bit_cast(bf16x2, a),
                                         __builtin_bit_cast(bf16x2, b), c, false);
}
#else
__device__ __forceinline__ float dot2b(u32 a, u32 b, float c){
  c = fmaf(b2f_lo(a), b2f_lo(b), c);
  return fmaf(b2f_hi(a), b2f_hi(b), c);
}
#endif

// ---- MFMA plumbing ----
typedef __attribute__((ext_vector_type(8))) short short8;
typedef __attribute__((ext_vector_type(4))) float f32x4;
__device__ __forceinline__ f32x4 mf32(uint4 a, uint4 b, f32x4 c){
  return __builtin_amdgcn_mfma_f32_16x16x32_bf16(
      __builtin_bit_cast(short8, a), __builtin_bit_cast(short8, b), c, 0, 0, 0);
}

// pre-transposed weight layout offsets in u16 units (padded, zero-filled)
#define OFF_WANG_V 0        // [128][40]
#define OFF_W1_V   5120     // [64][40]
#define OFF_WLIN_V 7680     // [128][136]
#define OFF_W2_V   25088    // [128][72]
#define OFF_WANG_K 34304    // [128][40]
#define OFF_W1_K   39424    // [64][40]
#define OFF_WLIN_K 41984    // [64][136]
#define OFF_W2_K   50688    // [64][72]
#define OFF_WOUT   55296    // [128][136]
#define WT_TOTAL   72704

__global__ __launch_bounds__(256) void zero_kernel(int* __restrict__ counts,
                                                   int* __restrict__ edge_ids)
{
  int i = blockIdx.x * 256 + threadIdx.x;
  if (i < NN) counts[i] = 0;
  if (i < NE) edge_ids[i] = 0;
}

// ---------------- one-time weight transpose/pad/bf16 prep
__global__ __launch_bounds__(256) void prep_w_kernel(
    const float* __restrict__ Wang_v, const float* __restrict__ W1_v,
    const float* __restrict__ Wlin_v, const float* __restrict__ W2_v,
    const float* __restrict__ Wang_k, const float* __restrict__ W1_k,
    const float* __restrict__ Wlin_k, const float* __restrict__ W2_k,
    const float* __restrict__ Wout,
    u16* __restrict__ wt)
{
  int idx = blockIdx.x * 256 + threadIdx.x;
  if (idx >= WT_TOTAL) return;
  float val = 0.f;
  if (idx < OFF_W1_V) {
    int l = idx - OFF_WANG_V, n = l / 40, k = l % 40;
    if (k < 16) val = Wang_v[n * 16 + k];
  } else if (idx < OFF_WLIN_V) {
    int l = idx - OFF_W1_V, n = l / 40, k = l % 40;
    if (k < 16) val = W1_v[k * 64 + n];
  } else if (idx < OFF_W2_V) {
    int l = idx - OFF_WLIN_V, n = l / 136, k = l % 136;
    if (k < 128) val = Wlin_v[k * 128 + n];
  } else if (idx < OFF_WANG_K) {
    int l = idx - OFF_W2_V, n = l / 72, k = l % 72;
    if (k < 64) val = W2_v[k * 128 + n];
  } else if (idx < OFF_W1_K) {
    int l = idx - OFF_WANG_K, n = l / 40, k = l % 40;
    if (k < 16) val = Wang_k[n * 16 + k];
  } else if (idx < OFF_WLIN_K) {
    int l = idx - OFF_W1_K, n = l / 40, k = l % 40;
    if (k < 16) val = W1_k[k * 64 + n];
  } else if (idx < OFF_W2_K) {
    int l = idx - OFF_WLIN_K, n = l / 136, k = l % 136;
    if (k < 128) val = Wlin_k[k * 64 + n];
  } else if (idx < OFF_WOUT) {
    int l = idx - OFF_W2_K, n = l / 72, k = l % 72;
    if (k < 64) val = W2_k[k * 64 + n];
  } else {                                   // WoutT: B^T[n][k] = Wout[k*128+n]
    int l = idx - OFF_WOUT, n = l / 136, k = l % 136;
    if (k < 128) val = Wout[k * 128 + n];
  }
  wt[idx] = f2b(val);
}

// ---------------- qw = (node_attr @ Wq) @ Wdot (per head), stored bf16 [N,64]
__global__ __launch_bounds__(256) void qw_kernel(const float* __restrict__ node_attr,
                                                 const float* __restrict__ Wq,
                                                 const float* __restrict__ Wdot,
                                                 u16* __restrict__ qw)
{
  __shared__ __align__(16) u16 sWqT[64 * 128];
  __shared__ float sWdot[64];
  __shared__ u32 s_x[4][64];
  __shared__ float s_q[4][64];
  int tid = threadIdx.x;
  for (int idx = tid; idx < 128 * 64; idx += 256) { int i = idx >> 6, j = idx & 63; sWqT[j * 128 + i] = f2b(Wq[idx]); }
  for (int idx = tid; idx < 64; idx += 256) sWdot[idx] = Wdot[idx];
  __syncthreads();
  int wv = tid >> 6, lane = tid & 63;
  int n = blockIdx.x * 4 + wv;
  if (n < NN) {
    float2 x2 = ((const float2*)(node_attr + (size_t)n * 128))[lane];
    s_x[wv][lane] = packb(x2.x, x2.y);
  } else {
    s_x[wv][lane] = 0;
  }
  __syncthreads();
  const uint4* wr = (const uint4*)(sWqT + lane * 128);
  float q = 0.f;
#pragma unroll
  for (int p = 0; p < 16; ++p) {
    uint4 c = wr[p];
    q = dot2b(c.x, s_x[wv][p * 4 + 0], q);
    q = dot2b(c.y, s_x[wv][p * 4 + 1], q);
    q = dot2b(c.z, s_x[wv][p * 4 + 2], q);
    q = dot2b(c.w, s_x[wv][p * 4 + 3], q);
  }
  s_q[wv][lane] = q;
  __syncthreads();
  if (n >= NN) return;
  int r = lane & 7, base = lane & 56;
  float acc = 0.f;
#pragma unroll
  for (int i = 0; i < 8; ++i) acc += s_q[wv][base + i] * sWdot[i * 8 + r];
  qw[(size_t)n * 64 + lane] = f2b(acc);
}

// ---------------- fused MFMA conv (v and k paths) + alpha, weights in registers
// block = 256 threads (4 waves) = 64 edges; 4 __syncthreads total.
__global__ __launch_bounds__(256, 2) void conv_fused_kernel(
    const float* __restrict__ node_attr, const float* __restrict__ edge_attr,
    const float* __restrict__ edge_sh, const int* __restrict__ edge_index,
    const float* __restrict__ b1v, const float* __restrict__ b1k,
    const u16* __restrict__ wt, const u16* __restrict__ qw,
    u16* __restrict__ v_out, float* __restrict__ alpha)
{
  __shared__ __align__(16) u16 sE[5120];       // EA[64][40] | SH[64][40]; later C_k[64][72]
  __shared__ __align__(16) u16 sTv[64 * 136];
  __shared__ __align__(16) u16 sTk[64 * 136];
  __shared__ __align__(16) u16 sHv[64 * 72];
  __shared__ __align__(16) u16 sHk[64 * 72];
  uint4* sE4 = (uint4*)sE;   u32* sE32 = (u32*)sE;
  uint4* sTv4 = (uint4*)sTv; uint4* sTk4 = (uint4*)sTk;
  uint4* sHv4 = (uint4*)sHv; uint4* sHk4 = (uint4*)sHk;
  const uint4* wt4 = (const uint4*)wt;

  const int tid = threadIdx.x;
  const int wv = tid >> 6, lane = tid & 63, lq = lane >> 4, ln = lane & 15;
  const int e0 = blockIdx.x * 64;
  const int nA = wv * 16 + ln, nB = (wv + 4) * 16 + ln;

  // q prefetch for alpha epilogue (held in regs through the kernel)
  int el = tid >> 2, p = tid & 3;
  int dq = edge_index[NE + e0 + el]; if ((u32)dq >= NN) dq = 0;
  const uint4* qptr = (const uint4*)(qw + (size_t)dq * 64 + p * 16);
  uint4 q0 = qptr[0], q1 = qptr[1];

  // weight B-fragments in registers (loaded once per block)
  uint4 rWangV0 = wt4[nA * 5 + lq],        rWangV1 = wt4[nB * 5 + lq];
  uint4 rW1V    = wt4[640 + nA * 5 + lq];
  uint4 rWangK0 = wt4[4288 + nA * 5 + lq], rWangK1 = wt4[4288 + nB * 5 + lq];
  uint4 rW1K    = wt4[4928 + nA * 5 + lq];
  uint4 rWlinV[2][4], rWlinK[4], rW2V[2][2], rW2K[2];
#pragma unroll
  for (int ks = 0; ks < 4; ++ks) {
    rWlinV[0][ks] = wt4[960 + nA * 17 + ks * 4 + lq];
    rWlinV[1][ks] = wt4[960 + nB * 17 + ks * 4 + lq];
    rWlinK[ks]    = wt4[5248 + nA * 17 + ks * 4 + lq];
  }
#pragma unroll
  for (int ks = 0; ks < 2; ++ks) {
    rW2V[0][ks] = wt4[3136 + nA * 9 + ks * 4 + lq];
    rW2V[1][ks] = wt4[3136 + nB * 9 + ks * 4 + lq];
    rW2K[ks]    = wt4[6336 + nA * 9 + ks * 4 + lq];
  }
  float biasV = b1v[nA], biasK = b1k[nA];

  // x gather: rows matching this lane's C-fragment rows
  int srcs[4][4];
#pragma unroll
  for (int et = 0; et < 4; ++et)
#pragma unroll
    for (int r = 0; r < 4; ++r) {
      int s = edge_index[e0 + et * 16 + lq * 4 + r];
      if ((u32)s >= NN) s = 0;
      srcs[et][r] = s;
    }
  float xf[2][4][4];
#pragma unroll
  for (int c = 0; c < 2; ++c) {
    int col = (wv + 4 * c) * 16 + ln;
#pragma unroll
    for (int et = 0; et < 4; ++et)
#pragma unroll
      for (int r = 0; r < 4; ++r)
        xf[c][et][r] = node_attr[(size_t)srcs[et][r] * 128 + col];
  }

  // stage EA/SH (zero-padded K 16->32)
  {
    int r = tid >> 2, kq = tid & 3;
    float4 ea = ((const float4*)(edge_attr + (size_t)(e0 + r) * 16))[kq];
    sE32[r * 20 + kq * 2]     = packb(ea.x, ea.y);
    sE32[r * 20 + kq * 2 + 1] = packb(ea.z, ea.w);
    sE32[r * 20 + 8 + kq]  = 0;
    sE32[r * 20 + 12 + kq] = 0;
    float4 sh = ((const float4*)(edge_sh + (size_t)(e0 + r) * 16))[kq];
    sE32[1280 + r * 20 + kq * 2]     = packb(sh.x, sh.y);
    sE32[1280 + r * 20 + kq * 2 + 1] = packb(sh.z, sh.w);
    sE32[1280 + r * 20 + 8 + kq]  = 0;
    sE32[1280 + r * 20 + 12 + kq] = 0;
  }
  __syncthreads();

  // phase1: hid + t for both paths
  const f32x4 z4 = {0.f, 0.f, 0.f, 0.f};
#pragma unroll
  for (int et = 0; et < 4; ++et) {
    uint4 aE = sE4[(et * 16 + ln) * 5 + lq];
    uint4 aS = sE4[320 + (et * 16 + ln) * 5 + lq];
    f32x4 hv = mf32(aE, rW1V, z4);
    f32x4 hk = mf32(aE, rW1K, z4);
    f32x4 t0v = mf32(aS, rWangV0, z4);
    f32x4 t1v = mf32(aS, rWangV1, z4);
    f32x4 t0k = mf32(aS, rWangK0, z4);
    f32x4 t1k = mf32(aS, rWangK1, z4);
    int rowb = et * 16 + lq * 4;
#pragma unroll
    for (int r = 0; r < 4; ++r) {
      sHv[(rowb + r) * 72 + nA] = f2b(fmaxf(hv[r] + biasV, 0.f));
      sHk[(rowb + r) * 72 + nA] = f2b(fmaxf(hk[r] + biasK, 0.f));
      sTv[(rowb + r) * 136 + nA] = f2b(t0v[r] * xf[0][et][r]);
      sTv[(rowb + r) * 136 + nB] = f2b(t1v[r] * xf[1][et][r]);
      sTk[(rowb + r) * 136 + nA] = f2b(t0k[r] * xf[0][et][r]);
      sTk[(rowb + r) * 136 + nB] = f2b(t1k[r] * xf[1][et][r]);
    }
  }
  __syncthreads();

  // phase2: all MFMA reads
  f32x4 a1v[2][4], a2v[2][4], a1k[4], a2k[4];
#pragma unroll
  for (int et = 0; et < 4; ++et) {
    int ar = et * 16 + ln;
    f32x4 acc;
    acc = z4;
#pragma unroll
    for (int ks = 0; ks < 4; ++ks) acc = mf32(sTv4[ar * 17 + ks * 4 + lq], rWlinV[0][ks], acc);
    a1v[0][et] = acc;
    acc = z4;
#pragma unroll
    for (int ks = 0; ks < 4; ++ks) acc = mf32(sTv4[ar * 17 + ks * 4 + lq], rWlinV[1][ks], acc);
    a1v[1][et] = acc;
    acc = z4;
#pragma unroll
    for (int ks = 0; ks < 4; ++ks) acc = mf32(sTk4[ar * 17 + ks * 4 + lq], rWlinK[ks], acc);
    a1k[et] = acc;
    acc = z4;
#pragma unroll
    for (int ks = 0; ks < 2; ++ks) acc = mf32(sHv4[ar * 9 + ks * 4 + lq], rW2V[0][ks], acc);
    a2v[0][et] = acc;
    acc = z4;
#pragma unroll
    for (int ks = 0; ks < 2; ++ks) acc = mf32(sHv4[ar * 9 + ks * 4 + lq], rW2V[1][ks], acc);
    a2v[1][et] = acc;
    acc = z4;
#pragma unroll
    for (int ks = 0; ks < 2; ++ks) acc = mf32(sHk4[ar * 9 + ks * 4 + lq], rW2K[ks], acc);
    a2k[et] = acc;
  }
  __syncthreads();

  // C writes (sTv reused for C_v; sE reused for C_k)
#pragma unroll
  for (int et = 0; et < 4; ++et) {
    int rowb = et * 16 + lq * 4;
#pragma unroll
    for (int r = 0; r < 4; ++r) {
      sTv[(rowb + r) * 136 + nA] = f2b(a1v[0][et][r] * a2v[0][et][r]);
      sTv[(rowb + r) * 136 + nB] = f2b(a1v[1][et][r] * a2v[1][et][r]);
      sE[(rowb + r) * 72 + nA]   = f2b(a1k[et][r] * a2k[et][r]);
    }
  }
  __syncthreads();

  // coalesced v store
  {
    int row = tid >> 2, seg = tid & 3;
    uint4* gp = (uint4*)(v_out + (size_t)(e0 + row) * 128);
#pragma unroll
    for (int i = 0; i < 4; ++i) gp[seg * 4 + i] = sTv4[row * 17 + seg * 4 + i];
  }
  // alpha epilogue
  {
    uint4 k0 = sE4[el * 9 + p * 2];
    uint4 k1 = sE4[el * 9 + p * 2 + 1];
    float a0 = 0.f, a1 = 0.f;
    a0 = dot2b(q0.x, k0.x, a0); a0 = dot2b(q0.y, k0.y, a0);
    a0 = dot2b(q0.z, k0.z, a0); a0 = dot2b(q0.w, k0.w, a0);
    a1 = dot2b(q1.x, k1.x, a1); a1 = dot2b(q1.y, k1.y, a1);
    a1 = dot2b(q1.z, k1.z, a1); a1 = dot2b(q1.w, k1.w, a1);
    ((float2*)(alpha + (size_t)(e0 + el) * 8))[p] = make_float2(a0, a1);
  }
}

// ---------------- CSR build
__global__ __launch_bounds__(256) void count_kernel(const int* __restrict__ edge_index,
                                                    int* __restrict__ counts)
{
  int e = blockIdx.x * 256 + threadIdx.x;
  if (e < NE) { int d = edge_index[NE + e]; if ((u32)d >= NN) d = 0; atomicAdd(&counts[d], 1); }
}

__global__ __launch_bounds__(1024) void scan_kernel(const int* __restrict__ counts,
                                                    int* __restrict__ row_ptr,
                                                    int* __restrict__ cursor)
{
  __shared__ int s[1024];
  int tid = threadIdx.x;
  int base = tid * STRIP;
  int sum = 0;
  for (int i = 0; i < STRIP; ++i) { int idx = base + i; sum += (idx < NN) ? counts[idx] : 0; }
  s[tid] = sum;
  __syncthreads();
  for (int off = 1; off < 1024; off <<= 1) {
    int v = s[tid];
    int add = (tid >= off) ? s[tid - off] : 0;
    __syncthreads();
    s[tid] = v + add;
    __syncthreads();
  }
  int running = (tid == 0) ? 0 : s[tid - 1];
  for (int i = 0; i < STRIP; ++i) {
    int idx = base + i;
    if (idx < NN) { row_ptr[idx] = running; cursor[idx] = running; running += counts[idx]; }
  }
  if (tid == 1023) row_ptr[NN] = running;
}

__global__ __launch_bounds__(256) void fill_kernel(const int* __restrict__ edge_index,
                                                   int* __restrict__ cursor,
                                                   int* __restrict__ edge_ids)
{
  int e = blockIdx.x * 256 + threadIdx.x;
  if (e < NE) {
    int dst = edge_index[NE + e]; if ((u32)dst >= NN) dst = 0;
    int pos = atomicAdd(&cursor[dst], 1);
    if ((u32)pos < NE) edge_ids[pos] = e;
  }
}

// ---------------- per-node softmax (one wave per node, shuffle-only) +
// weighted V gather + MFMA @Wout epilogue over 16-node batches
__global__ __launch_bounds__(256) void out_kernel(
    const int* __restrict__ row_ptr, const int* __restrict__ edge_ids,
    const float* __restrict__ alpha, const u16* __restrict__ v_e,
    const u16* __restrict__ wt, float* __restrict__ out)
{
  __shared__ __align__(16) u16 sAgg[16 * 136];
  u32* sAgg32 = (u32*)sAgg;
  uint4* sAgg4 = (uint4*)sAgg;
  const uint4* wt4 = (const uint4*)wt;
  const int tid = threadIdx.x, wv = tid >> 6, lane = tid & 63, lq = lane >> 4, ln = lane & 15;
  const f32x4 z4 = {0.f, 0.f, 0.f, 0.f};
  // WoutT B-fragments in registers (cols ct = wv*2 + c)
  uint4 rWT[2][4];
#pragma unroll
  for (int c = 0; c < 2; ++c) {
    int n = (wv * 2 + c) * 16 + ln;
#pragma unroll
    for (int ks = 0; ks < 4; ++ks) rWT[c][ks] = wt4[6912 + n * 17 + ks * 4 + lq];
  }
  const int hh0 = lane >> 4, hh1 = 4 + hh0;
  const int h = lane & 7, slot = lane >> 3;
  for (int grp = blockIdx.x; grp < 3125; grp += OUT_GRID) {
#pragma unroll 1
    for (int i = 0; i < 4; ++i) {
      int n = grp * 16 + wv * 4 + i;
      int beg = row_ptr[n], end = row_ptr[n + 1];
      if (beg < 0) beg = 0; if (beg > NE) beg = NE;
      if (end < beg) end = beg; if (end > NE) end = NE;
      int deg = end - beg;
      float m = -3.0e38f;
      for (int j = slot; j < deg; j += 8) {
        int e = edge_ids[beg + j]; if ((u32)e >= NE) e = 0;
        m = fmaxf(m, alpha[(size_t)e * 8 + h]);
      }
      m = fmaxf(m, __shfl_xor(m, 8, 64));
      m = fmaxf(m, __shfl_xor(m, 16, 64));
      m = fmaxf(m, __shfl_xor(m, 32, 64));
      float dsum = 0.f;
      for (int j = slot; j < deg; j += 8) {
        int e = edge_ids[beg + j]; if ((u32)e >= NE) e = 0;
        dsum += __expf(alpha[(size_t)e * 8 + h] - m);
      }
      dsum += __shfl_xor(dsum, 8, 64);
      dsum += __shfl_xor(dsum, 16, 64);
      dsum += __shfl_xor(dsum, 32, 64);
      float am0 = __shfl(m, hh0, 64),  am1 = __shfl(m, hh1, 64);
      float di0 = 1.f / __shfl(dsum, hh0, 64), di1 = 1.f / __shfl(dsum, hh1, 64);
      float acc0 = 0.f, acc1 = 0.f;
      for (int j = 0; j < deg; ++j) {
        int e = edge_ids[beg + j]; if ((u32)e >= NE) e = 0;
        const float* ap = alpha + (size_t)e * 8;
        float at0 = __expf(ap[hh0] - am0) * di0;
        float at1 = __expf(ap[hh1] - am1) * di1;
        const u16* vp = v_e + (size_t)e * 128;
        acc0 += at0 * b2f(vp[lane]);
        acc1 += at1 * b2f(vp[64 + lane]);
      }
      int g = wv * 4 + i;
      float n0 = __shfl_xor(acc0, 1, 64);
      float n1 = __shfl_xor(acc1, 1, 64);
      if ((lane & 1) == 0) {
        sAgg32[g * 68 + (lane >> 1)]      = packb(acc0, n0);
        sAgg32[g * 68 + 32 + (lane >> 1)] = packb(acc1, n1);
      }
    }
    __syncthreads();
#pragma unroll
    for (int c = 0; c < 2; ++c) {
      f32x4 acc = z4;
#pragma unroll
      for (int ks = 0; ks < 4; ++ks) acc = mf32(sAgg4[ln * 17 + ks * 4 + lq], rWT[c][ks], acc);
      int col = (wv * 2 + c) * 16 + ln;
#pragma unroll
      for (int r = 0; r < 4; ++r)
        out[(size_t)(grp * 16 + lq * 4 + r) * 128 + col] = acc[r];
    }
    __syncthreads();
  }
}

extern "C" void kernel_launch(void* const* d_in, const int* in_sizes, int n_in,
                              void* d_out, int out_size, void* d_ws, size_t ws_size,
                              hipStream_t stream)
{
  const float* node_attr = (const float*)d_in[0];
  const float* edge_attr = (const float*)d_in[1];
  const float* edge_sh   = (const float*)d_in[2];
  const float* Wq        = (const float*)d_in[3];
  const float* Wang_k    = (const float*)d_in[4];
  const float* Wlin_k    = (const float*)d_in[5];
  const float* W1k       = (const float*)d_in[6];
  const float* b1k       = (const float*)d_in[7];
  const float* W2k       = (const float*)d_in[8];
  const float* Wang_v    = (const float*)d_in[9];
  const float* Wlin_v    = (const float*)d_in[10];
  const float* W1v       = (const float*)d_in[11];
  const float* b1v       = (const float*)d_in[12];
  const float* W2v       = (const float*)d_in[13];
  const float* Wdot      = (const float*)d_in[14];
  const float* Wout      = (const float*)d_in[15];
  const int* edge_index  = (const int*)d_in[16];
  float* out = (float*)d_out;

  char* ws = (char*)d_ws;
  u16*   v_e      = (u16*)(ws + 0);                 // E*128*2  = 204,800,000
  float* alpha    = (float*)(ws + 204800000);       // E*8*4    =  25,600,000
  u16*   qw       = (u16*)(ws + 230400000);         // N*64*2   =   6,400,000
  int*   counts   = (int*)(ws + 236800000);         // 200,064
  int*   row_ptr  = (int*)(ws + 237000064);         // 200,064
  int*   cursor   = (int*)(ws + 237200128);         // 200,064
  int*   edge_ids = (int*)(ws + 237400192);         // 3,200,000
  u16*   wt       = (u16*)(ws + 240600192);         // 145,408 -> total 240,745,600

  zero_kernel<<<dim3((NE + 255) / 256), dim3(256), 0, stream>>>(counts, edge_ids);
  prep_w_kernel<<<dim3((WT_TOTAL + 255) / 256), dim3(256), 0, stream>>>(
      Wang_v, W1v, Wlin_v, W2v, Wang_k, W1k, Wlin_k, W2k, Wout, wt);
  qw_kernel<<<dim3((NN + 3) / 4), dim3(256), 0, stream>>>(node_attr, Wq, Wdot, qw);
  conv_fused_kernel<<<dim3(NE / 64), dim3(256), 0, stream>>>(
      node_attr, edge_attr, edge_sh, edge_index, b1v, b1k, wt, qw, v_e, alpha);
  count_kernel<<<dim3((NE + 255) / 256), dim3(256), 0, stream>>>(edge_index, counts);
  scan_kernel<<<dim3(1), dim3(1024), 0, stream>>>(counts, row_ptr, cursor);
  fill_kernel<<<dim3((NE + 255) / 256), dim3(256), 0, stream>>>(edge_index, cursor, edge_ids);
  out_kernel<<<dim3(OUT_GRID), dim3(256), 0, stream>>>(row_ptr, edge_ids, alpha, v_e, wt, out);
}

// Round 7
// 923.367 us; speedup vs baseline: 2.0179x; 1.2044x over previous
//
#include <hip/hip_runtime.h>
#include <stdint.h>

#define NN 50000
#define NE 800000
#define STRIP 49   // ceil(NN/1024)

typedef unsigned int u32;
typedef uint16_t u16;

__device__ __forceinline__ float b2f(u16 u){ return __builtin_bit_cast(float, (u32)((u32)u << 16)); }
__device__ __forceinline__ float b2f_lo(u32 p){ return __builtin_bit_cast(float, p << 16); }
__device__ __forceinline__ float b2f_hi(u32 p){ return __builtin_bit_cast(float, p & 0xffff0000u); }
__device__ __forceinline__ u32 f2b_bits(float f){ u32 u = __builtin_bit_cast(u32, f); return (u + 0x7fffu + ((u >> 16) & 1u)) >> 16; }
__device__ __forceinline__ u16 f2b(float f){ return (u16)f2b_bits(f); }
__device__ __forceinline__ u32 packb(float lo, float hi){ return f2b_bits(lo) | (f2b_bits(hi) << 16); }

typedef __bf16 bf16x2 __attribute__((ext_vector_type(2)));
#if defined(__has_builtin)
#if __has_builtin(__builtin_amdgcn_fdot2_f32_bf16)
#define HAVE_DOT2_BUILTIN 1
#endif
#endif

#ifdef HAVE_DOT2_BUILTIN
__device__ __forceinline__ float dot2b(u32 a, u32 b, float c){
  return __builtin_amdgcn_fdot2_f32_bf16(__builtin_bit_cast(bf16x2, a),
                                         __builtin_bit_cast(bf16x2, b), c, false);
}
#else
__device__ __forceinline__ float dot2b(u32 a, u32 b, float c){
  c = fmaf(b2f_lo(a), b2f_lo(b), c);
  return fmaf(b2f_hi(a), b2f_hi(b), c);
}
#endif

// ---- MFMA plumbing ----
typedef __attribute__((ext_vector_type(8))) short short8;
typedef __attribute__((ext_vector_type(4))) float f32x4;
__device__ __forceinline__ f32x4 mf32(uint4 a, uint4 b, f32x4 c){
  return __builtin_amdgcn_mfma_f32_16x16x32_bf16(
      __builtin_bit_cast(short8, a), __builtin_bit_cast(short8, b), c, 0, 0, 0);
}

// pre-transposed weight layout offsets in u16 units (padded, zero-filled)
#define OFF_WANG_V 0        // [128][40]
#define OFF_W1_V   5120     // [64][40]
#define OFF_WLIN_V 7680     // [128][136]
#define OFF_W2_V   25088    // [128][72]
#define OFF_WANG_K 34304    // [128][40]
#define OFF_W1_K   39424    // [64][40]
#define OFF_WLIN_K 41984    // [64][136]
#define OFF_W2_K   50688    // [64][72]
#define OFF_WOUT   55296    // [128][136]
#define WT_TOTAL   72704

__global__ __launch_bounds__(256) void zero_kernel(int* __restrict__ counts,
                                                   int* __restrict__ edge_ids)
{
  int i = blockIdx.x * 256 + threadIdx.x;
  if (i < NN) counts[i] = 0;
  if (i < NE) edge_ids[i] = 0;
}

// ---------------- one-time weight transpose/pad/bf16 prep
__global__ __launch_bounds__(256) void prep_w_kernel(
    const float* __restrict__ Wang_v, const float* __restrict__ W1_v,
    const float* __restrict__ Wlin_v, const float* __restrict__ W2_v,
    const float* __restrict__ Wang_k, const float* __restrict__ W1_k,
    const float* __restrict__ Wlin_k, const float* __restrict__ W2_k,
    const float* __restrict__ Wout,
    u16* __restrict__ wt)
{
  int idx = blockIdx.x * 256 + threadIdx.x;
  if (idx >= WT_TOTAL) return;
  float val = 0.f;
  if (idx < OFF_W1_V) {
    int l = idx - OFF_WANG_V, n = l / 40, k = l % 40;
    if (k < 16) val = Wang_v[n * 16 + k];
  } else if (idx < OFF_WLIN_V) {
    int l = idx - OFF_W1_V, n = l / 40, k = l % 40;
    if (k < 16) val = W1_v[k * 64 + n];
  } else if (idx < OFF_W2_V) {
    int l = idx - OFF_WLIN_V, n = l / 136, k = l % 136;
    if (k < 128) val = Wlin_v[k * 128 + n];
  } else if (idx < OFF_WANG_K) {
    int l = idx - OFF_W2_V, n = l / 72, k = l % 72;
    if (k < 64) val = W2_v[k * 128 + n];
  } else if (idx < OFF_W1_K) {
    int l = idx - OFF_WANG_K, n = l / 40, k = l % 40;
    if (k < 16) val = Wang_k[n * 16 + k];
  } else if (idx < OFF_WLIN_K) {
    int l = idx - OFF_W1_K, n = l / 40, k = l % 40;
    if (k < 16) val = W1_k[k * 64 + n];
  } else if (idx < OFF_W2_K) {
    int l = idx - OFF_WLIN_K, n = l / 136, k = l % 136;
    if (k < 128) val = Wlin_k[k * 64 + n];
  } else if (idx < OFF_WOUT) {
    int l = idx - OFF_W2_K, n = l / 72, k = l % 72;
    if (k < 64) val = W2_k[k * 64 + n];
  } else {                                   // WoutT: B^T[n][k] = Wout[k*128+n]
    int l = idx - OFF_WOUT, n = l / 136, k = l % 136;
    if (k < 128) val = Wout[k * 128 + n];
  }
  wt[idx] = f2b(val);
}

// ---------------- qw = (node_attr @ Wq) @ Wdot (per head), stored bf16 [N,64]
__global__ __launch_bounds__(256) void qw_kernel(const float* __restrict__ node_attr,
                                                 const float* __restrict__ Wq,
                                                 const float* __restrict__ Wdot,
                                                 u16* __restrict__ qw)
{
  __shared__ __align__(16) u16 sWqT[64 * 128];
  __shared__ float sWdot[64];
  __shared__ u32 s_x[4][64];
  __shared__ float s_q[4][64];
  int tid = threadIdx.x;
  for (int idx = tid; idx < 128 * 64; idx += 256) { int i = idx >> 6, j = idx & 63; sWqT[j * 128 + i] = f2b(Wq[idx]); }
  for (int idx = tid; idx < 64; idx += 256) sWdot[idx] = Wdot[idx];
  __syncthreads();
  int wv = tid >> 6, lane = tid & 63;
  int n = blockIdx.x * 4 + wv;
  if (n < NN) {
    float2 x2 = ((const float2*)(node_attr + (size_t)n * 128))[lane];
    s_x[wv][lane] = packb(x2.x, x2.y);
  } else {
    s_x[wv][lane] = 0;
  }
  __syncthreads();
  const uint4* wr = (const uint4*)(sWqT + lane * 128);
  float q = 0.f;
#pragma unroll
  for (int p = 0; p < 16; ++p) {
    uint4 c = wr[p];
    q = dot2b(c.x, s_x[wv][p * 4 + 0], q);
    q = dot2b(c.y, s_x[wv][p * 4 + 1], q);
    q = dot2b(c.z, s_x[wv][p * 4 + 2], q);
    q = dot2b(c.w, s_x[wv][p * 4 + 3], q);
  }
  s_q[wv][lane] = q;
  __syncthreads();
  if (n >= NN) return;
  int r = lane & 7, base = lane & 56;
  float acc = 0.f;
#pragma unroll
  for (int i = 0; i < 8; ++i) acc += s_q[wv][base + i] * sWdot[i * 8 + r];
  qw[(size_t)n * 64 + lane] = f2b(acc);
}

// ---------------- fused MFMA conv (v and k paths) + alpha, weights in registers
__global__ __launch_bounds__(256, 2) void conv_fused_kernel(
    const float* __restrict__ node_attr, const float* __restrict__ edge_attr,
    const float* __restrict__ edge_sh, const int* __restrict__ edge_index,
    const float* __restrict__ b1v, const float* __restrict__ b1k,
    const u16* __restrict__ wt, const u16* __restrict__ qw,
    u16* __restrict__ v_out, float* __restrict__ alpha)
{
  __shared__ __align__(16) u16 sE[5120];       // EA[64][40] | SH[64][40]; later C_k[64][72]
  __shared__ __align__(16) u16 sTv[64 * 136];
  __shared__ __align__(16) u16 sTk[64 * 136];
  __shared__ __align__(16) u16 sHv[64 * 72];
  __shared__ __align__(16) u16 sHk[64 * 72];
  uint4* sE4 = (uint4*)sE;   u32* sE32 = (u32*)sE;
  uint4* sTv4 = (uint4*)sTv; uint4* sTk4 = (uint4*)sTk;
  uint4* sHv4 = (uint4*)sHv; uint4* sHk4 = (uint4*)sHk;
  const uint4* wt4 = (const uint4*)wt;

  const int tid = threadIdx.x;
  const int wv = tid >> 6, lane = tid & 63, lq = lane >> 4, ln = lane & 15;
  const int e0 = blockIdx.x * 64;
  const int nA = wv * 16 + ln, nB = (wv + 4) * 16 + ln;

  int el = tid >> 2, p = tid & 3;
  int dq = edge_index[NE + e0 + el]; if ((u32)dq >= NN) dq = 0;
  const uint4* qptr = (const uint4*)(qw + (size_t)dq * 64 + p * 16);
  uint4 q0 = qptr[0], q1 = qptr[1];

  uint4 rWangV0 = wt4[nA * 5 + lq],        rWangV1 = wt4[nB * 5 + lq];
  uint4 rW1V    = wt4[640 + nA * 5 + lq];
  uint4 rWangK0 = wt4[4288 + nA * 5 + lq], rWangK1 = wt4[4288 + nB * 5 + lq];
  uint4 rW1K    = wt4[4928 + nA * 5 + lq];
  uint4 rWlinV[2][4], rWlinK[4], rW2V[2][2], rW2K[2];
#pragma unroll
  for (int ks = 0; ks < 4; ++ks) {
    rWlinV[0][ks] = wt4[960 + nA * 17 + ks * 4 + lq];
    rWlinV[1][ks] = wt4[960 + nB * 17 + ks * 4 + lq];
    rWlinK[ks]    = wt4[5248 + nA * 17 + ks * 4 + lq];
  }
#pragma unroll
  for (int ks = 0; ks < 2; ++ks) {
    rW2V[0][ks] = wt4[3136 + nA * 9 + ks * 4 + lq];
    rW2V[1][ks] = wt4[3136 + nB * 9 + ks * 4 + lq];
    rW2K[ks]    = wt4[6336 + nA * 9 + ks * 4 + lq];
  }
  float biasV = b1v[nA], biasK = b1k[nA];

  int srcs[4][4];
#pragma unroll
  for (int et = 0; et < 4; ++et)
#pragma unroll
    for (int r = 0; r < 4; ++r) {
      int s = edge_index[e0 + et * 16 + lq * 4 + r];
      if ((u32)s >= NN) s = 0;
      srcs[et][r] = s;
    }
  float xf[2][4][4];
#pragma unroll
  for (int c = 0; c < 2; ++c) {
    int col = (wv + 4 * c) * 16 + ln;
#pragma unroll
    for (int et = 0; et < 4; ++et)
#pragma unroll
      for (int r = 0; r < 4; ++r)
        xf[c][et][r] = node_attr[(size_t)srcs[et][r] * 128 + col];
  }

  {
    int r = tid >> 2, kq = tid & 3;
    float4 ea = ((const float4*)(edge_attr + (size_t)(e0 + r) * 16))[kq];
    sE32[r * 20 + kq * 2]     = packb(ea.x, ea.y);
    sE32[r * 20 + kq * 2 + 1] = packb(ea.z, ea.w);
    sE32[r * 20 + 8 + kq]  = 0;
    sE32[r * 20 + 12 + kq] = 0;
    float4 sh = ((const float4*)(edge_sh + (size_t)(e0 + r) * 16))[kq];
    sE32[1280 + r * 20 + kq * 2]     = packb(sh.x, sh.y);
    sE32[1280 + r * 20 + kq * 2 + 1] = packb(sh.z, sh.w);
    sE32[1280 + r * 20 + 8 + kq]  = 0;
    sE32[1280 + r * 20 + 12 + kq] = 0;
  }
  __syncthreads();

  const f32x4 z4 = {0.f, 0.f, 0.f, 0.f};
#pragma unroll
  for (int et = 0; et < 4; ++et) {
    uint4 aE = sE4[(et * 16 + ln) * 5 + lq];
    uint4 aS = sE4[320 + (et * 16 + ln) * 5 + lq];
    f32x4 hv = mf32(aE, rW1V, z4);
    f32x4 hk = mf32(aE, rW1K, z4);
    f32x4 t0v = mf32(aS, rWangV0, z4);
    f32x4 t1v = mf32(aS, rWangV1, z4);
    f32x4 t0k = mf32(aS, rWangK0, z4);
    f32x4 t1k = mf32(aS, rWangK1, z4);
    int rowb = et * 16 + lq * 4;
#pragma unroll
    for (int r = 0; r < 4; ++r) {
      sHv[(rowb + r) * 72 + nA] = f2b(fmaxf(hv[r] + biasV, 0.f));
      sHk[(rowb + r) * 72 + nA] = f2b(fmaxf(hk[r] + biasK, 0.f));
      sTv[(rowb + r) * 136 + nA] = f2b(t0v[r] * xf[0][et][r]);
      sTv[(rowb + r) * 136 + nB] = f2b(t1v[r] * xf[1][et][r]);
      sTk[(rowb + r) * 136 + nA] = f2b(t0k[r] * xf[0][et][r]);
      sTk[(rowb + r) * 136 + nB] = f2b(t1k[r] * xf[1][et][r]);
    }
  }
  __syncthreads();

  f32x4 a1v[2][4], a2v[2][4], a1k[4], a2k[4];
#pragma unroll
  for (int et = 0; et < 4; ++et) {
    int ar = et * 16 + ln;
    f32x4 acc;
    acc = z4;
#pragma unroll
    for (int ks = 0; ks < 4; ++ks) acc = mf32(sTv4[ar * 17 + ks * 4 + lq], rWlinV[0][ks], acc);
    a1v[0][et] = acc;
    acc = z4;
#pragma unroll
    for (int ks = 0; ks < 4; ++ks) acc = mf32(sTv4[ar * 17 + ks * 4 + lq], rWlinV[1][ks], acc);
    a1v[1][et] = acc;
    acc = z4;
#pragma unroll
    for (int ks = 0; ks < 4; ++ks) acc = mf32(sTk4[ar * 17 + ks * 4 + lq], rWlinK[ks], acc);
    a1k[et] = acc;
    acc = z4;
#pragma unroll
    for (int ks = 0; ks < 2; ++ks) acc = mf32(sHv4[ar * 9 + ks * 4 + lq], rW2V[0][ks], acc);
    a2v[0][et] = acc;
    acc = z4;
#pragma unroll
    for (int ks = 0; ks < 2; ++ks) acc = mf32(sHv4[ar * 9 + ks * 4 + lq], rW2V[1][ks], acc);
    a2v[1][et] = acc;
    acc = z4;
#pragma unroll
    for (int ks = 0; ks < 2; ++ks) acc = mf32(sHk4[ar * 9 + ks * 4 + lq], rW2K[ks], acc);
    a2k[et] = acc;
  }
  __syncthreads();

#pragma unroll
  for (int et = 0; et < 4; ++et) {
    int rowb = et * 16 + lq * 4;
#pragma unroll
    for (int r = 0; r < 4; ++r) {
      sTv[(rowb + r) * 136 + nA] = f2b(a1v[0][et][r] * a2v[0][et][r]);
      sTv[(rowb + r) * 136 + nB] = f2b(a1v[1][et][r] * a2v[1][et][r]);
      sE[(rowb + r) * 72 + nA]   = f2b(a1k[et][r] * a2k[et][r]);
    }
  }
  __syncthreads();

  {
    int row = tid >> 2, seg = tid & 3;
    uint4* gp = (uint4*)(v_out + (size_t)(e0 + row) * 128);
#pragma unroll
    for (int i = 0; i < 4; ++i) gp[seg * 4 + i] = sTv4[row * 17 + seg * 4 + i];
  }
  {
    uint4 k0 = sE4[el * 9 + p * 2];
    uint4 k1 = sE4[el * 9 + p * 2 + 1];
    float a0 = 0.f, a1 = 0.f;
    a0 = dot2b(q0.x, k0.x, a0); a0 = dot2b(q0.y, k0.y, a0);
    a0 = dot2b(q0.z, k0.z, a0); a0 = dot2b(q0.w, k0.w, a0);
    a1 = dot2b(q1.x, k1.x, a1); a1 = dot2b(q1.y, k1.y, a1);
    a1 = dot2b(q1.z, k1.z, a1); a1 = dot2b(q1.w, k1.w, a1);
    ((float2*)(alpha + (size_t)(e0 + el) * 8))[p] = make_float2(a0, a1);
  }
}

// ---------------- CSR build
__global__ __launch_bounds__(256) void count_kernel(const int* __restrict__ edge_index,
                                                    int* __restrict__ counts)
{
  int e = blockIdx.x * 256 + threadIdx.x;
  if (e < NE) { int d = edge_index[NE + e]; if ((u32)d >= NN) d = 0; atomicAdd(&counts[d], 1); }
}

__global__ __launch_bounds__(1024) void scan_kernel(const int* __restrict__ counts,
                                                    int* __restrict__ row_ptr,
                                                    int* __restrict__ cursor)
{
  __shared__ int s[1024];
  int tid = threadIdx.x;
  int base = tid * STRIP;
  int sum = 0;
  for (int i = 0; i < STRIP; ++i) { int idx = base + i; sum += (idx < NN) ? counts[idx] : 0; }
  s[tid] = sum;
  __syncthreads();
  for (int off = 1; off < 1024; off <<= 1) {
    int v = s[tid];
    int add = (tid >= off) ? s[tid - off] : 0;
    __syncthreads();
    s[tid] = v + add;
    __syncthreads();
  }
  int running = (tid == 0) ? 0 : s[tid - 1];
  for (int i = 0; i < STRIP; ++i) {
    int idx = base + i;
    if (idx < NN) { row_ptr[idx] = running; cursor[idx] = running; running += counts[idx]; }
  }
  if (tid == 1023) row_ptr[NN] = running;
}

__global__ __launch_bounds__(256) void fill_kernel(const int* __restrict__ edge_index,
                                                   int* __restrict__ cursor,
                                                   int* __restrict__ edge_ids)
{
  int e = blockIdx.x * 256 + threadIdx.x;
  if (e < NE) {
    int dst = edge_index[NE + e]; if ((u32)dst >= NN) dst = 0;
    int pos = atomicAdd(&cursor[dst], 1);
    if ((u32)pos < NE) edge_ids[pos] = e;
  }
}

// ---------------- per-node single-pass online softmax + V gather (u32 loads,
// 4x unrolled) + MFMA @Wout epilogue. One wave per node, 16 nodes per block.
#define OUPD(aa, ww)                                                   \
  { float mn = fmaxf(m, (aa));                                         \
    float sc = __expf(m - mn);                                         \
    float pw = __expf((aa) - mn);                                      \
    l = l * sc + pw;                                                   \
    accA = accA * sc + pw * b2f_lo(ww);                                \
    accB = accB * sc + pw * b2f_hi(ww);                                \
    m = mn; }

__global__ __launch_bounds__(256) void out_kernel(
    const int* __restrict__ row_ptr, const int* __restrict__ edge_ids,
    const float* __restrict__ alpha, const u16* __restrict__ v_e,
    const u16* __restrict__ wt, float* __restrict__ out)
{
  __shared__ __align__(16) u16 sAgg[16 * 136];
  u32* sAgg32 = (u32*)sAgg;
  uint4* sAgg4 = (uint4*)sAgg;
  const uint4* wt4 = (const uint4*)wt;
  const u32* v32 = (const u32*)v_e;
  const int tid = threadIdx.x, wv = tid >> 6, lane = tid & 63, lq = lane >> 4, ln = lane & 15;
  const f32x4 z4 = {0.f, 0.f, 0.f, 0.f};
  uint4 rWT[2][4];
#pragma unroll
  for (int c = 0; c < 2; ++c) {
    int n = (wv * 2 + c) * 16 + ln;
#pragma unroll
    for (int ks = 0; ks < 4; ++ks) rWT[c][ks] = wt4[6912 + n * 17 + ks * 4 + lq];
  }
  const int hh = lane >> 3;   // head of cols {2*lane, 2*lane+1}
  const int grp = blockIdx.x;
#pragma unroll 1
  for (int i = 0; i < 4; ++i) {
    int n = grp * 16 + wv * 4 + i;
    int beg = row_ptr[n], end = row_ptr[n + 1];
    if (beg < 0) beg = 0; if (beg > NE) beg = NE;
    if (end < beg) end = beg; if (end > NE) end = NE;
    int deg = end - beg;
    float m = -3.0e38f, l = 0.f, accA = 0.f, accB = 0.f;
    int j = 0;
#pragma unroll 1
    for (; j + 4 <= deg; j += 4) {
      int e0 = edge_ids[beg + j],     e1 = edge_ids[beg + j + 1];
      int e2 = edge_ids[beg + j + 2], e3 = edge_ids[beg + j + 3];
      if ((u32)e0 >= NE) e0 = 0; if ((u32)e1 >= NE) e1 = 0;
      if ((u32)e2 >= NE) e2 = 0; if ((u32)e3 >= NE) e3 = 0;
      float a0 = alpha[(size_t)e0 * 8 + hh]; u32 w0 = v32[(size_t)e0 * 64 + lane];
      float a1 = alpha[(size_t)e1 * 8 + hh]; u32 w1 = v32[(size_t)e1 * 64 + lane];
      float a2 = alpha[(size_t)e2 * 8 + hh]; u32 w2 = v32[(size_t)e2 * 64 + lane];
      float a3 = alpha[(size_t)e3 * 8 + hh]; u32 w3 = v32[(size_t)e3 * 64 + lane];
      OUPD(a0, w0); OUPD(a1, w1); OUPD(a2, w2); OUPD(a3, w3);
    }
#pragma unroll 1
    for (; j < deg; ++j) {
      int e = edge_ids[beg + j]; if ((u32)e >= NE) e = 0;
      float a = alpha[(size_t)e * 8 + hh]; u32 w = v32[(size_t)e * 64 + lane];
      OUPD(a, w);
    }
    float inv = (l > 0.f) ? (1.f / l) : 0.f;
    accA *= inv; accB *= inv;
    sAgg32[(wv * 4 + i) * 68 + lane] = packb(accA, accB);
  }
  __syncthreads();
#pragma unroll
  for (int c = 0; c < 2; ++c) {
    f32x4 acc = z4;
#pragma unroll
    for (int ks = 0; ks < 4; ++ks) acc = mf32(sAgg4[ln * 17 + ks * 4 + lq], rWT[c][ks], acc);
    int col = (wv * 2 + c) * 16 + ln;
#pragma unroll
    for (int r = 0; r < 4; ++r)
      out[(size_t)(grp * 16 + lq * 4 + r) * 128 + col] = acc[r];
  }
}

extern "C" void kernel_launch(void* const* d_in, const int* in_sizes, int n_in,
                              void* d_out, int out_size, void* d_ws, size_t ws_size,
                              hipStream_t stream)
{
  const float* node_attr = (const float*)d_in[0];
  const float* edge_attr = (const float*)d_in[1];
  const float* edge_sh   = (const float*)d_in[2];
  const float* Wq        = (const float*)d_in[3];
  const float* Wang_k    = (const float*)d_in[4];
  const float* Wlin_k    = (const float*)d_in[5];
  const float* W1k       = (const float*)d_in[6];
  const float* b1k       = (const float*)d_in[7];
  const float* W2k       = (const float*)d_in[8];
  const float* Wang_v    = (const float*)d_in[9];
  const float* Wlin_v    = (const float*)d_in[10];
  const float* W1v       = (const float*)d_in[11];
  const float* b1v       = (const float*)d_in[12];
  const float* W2v       = (const float*)d_in[13];
  const float* Wdot      = (const float*)d_in[14];
  const float* Wout      = (const float*)d_in[15];
  const int* edge_index  = (const int*)d_in[16];
  float* out = (float*)d_out;

  char* ws = (char*)d_ws;
  u16*   v_e      = (u16*)(ws + 0);                 // E*128*2  = 204,800,000
  float* alpha    = (float*)(ws + 204800000);       // E*8*4    =  25,600,000
  u16*   qw       = (u16*)(ws + 230400000);         // N*64*2   =   6,400,000
  int*   counts   = (int*)(ws + 236800000);         // 200,064
  int*   row_ptr  = (int*)(ws + 237000064);         // 200,064
  int*   cursor   = (int*)(ws + 237200128);         // 200,064
  int*   edge_ids = (int*)(ws + 237400192);         // 3,200,000
  u16*   wt       = (u16*)(ws + 240600192);         // 145,408 -> total 240,745,600

  zero_kernel<<<dim3((NE + 255) / 256), dim3(256), 0, stream>>>(counts, edge_ids);
  prep_w_kernel<<<dim3((WT_TOTAL + 255) / 256), dim3(256), 0, stream>>>(
      Wang_v, W1v, Wlin_v, W2v, Wang_k, W1k, Wlin_k, W2k, Wout, wt);
  qw_kernel<<<dim3((NN + 3) / 4), dim3(256), 0, stream>>>(node_attr, Wq, Wdot, qw);
  conv_fused_kernel<<<dim3(NE / 64), dim3(256), 0, stream>>>(
      node_attr, edge_attr, edge_sh, edge_index, b1v, b1k, wt, qw, v_e, alpha);
  count_kernel<<<dim3((NE + 255) / 256), dim3(256), 0, stream>>>(edge_index, counts);
  scan_kernel<<<dim3(1), dim3(1024), 0, stream>>>(counts, row_ptr, cursor);
  fill_kernel<<<dim3((NE + 255) / 256), dim3(256), 0, stream>>>(edge_index, cursor, edge_ids);
  out_kernel<<<dim3(3125), dim3(256), 0, stream>>>(row_ptr, edge_ids, alpha, v_e, wt, out);
}

// Round 8
// 678.690 us; speedup vs baseline: 2.7454x; 1.3605x over previous
//
#include <hip/hip_runtime.h>
#include <stdint.h>

#define NN 50000
#define NE 800000
#define STRIP 49   // ceil(NN/1024)

typedef unsigned int u32;
typedef uint16_t u16;

__device__ __forceinline__ float b2f(u16 u){ return __builtin_bit_cast(float, (u32)((u32)u << 16)); }
__device__ __forceinline__ float b2f_lo(u32 p){ return __builtin_bit_cast(float, p << 16); }
__device__ __forceinline__ float b2f_hi(u32 p){ return __builtin_bit_cast(float, p & 0xffff0000u); }
__device__ __forceinline__ u32 f2b_bits(float f){ u32 u = __builtin_bit_cast(u32, f); return (u + 0x7fffu + ((u >> 16) & 1u)) >> 16; }
__device__ __forceinline__ u16 f2b(float f){ return (u16)f2b_bits(f); }
__device__ __forceinline__ u32 packb(float lo, float hi){ return f2b_bits(lo) | (f2b_bits(hi) << 16); }

typedef __bf16 bf16x2 __attribute__((ext_vector_type(2)));
#if defined(__has_builtin)
#if __has_builtin(__builtin_amdgcn_fdot2_f32_bf16)
#define HAVE_DOT2_BUILTIN 1
#endif
#endif

#ifdef HAVE_DOT2_BUILTIN
__device__ __forceinline__ float dot2b(u32 a, u32 b, float c){
  return __builtin_amdgcn_fdot2_f32_bf16(__builtin_bit_cast(bf16x2, a),
                                         __builtin_bit_cast(bf16x2, b), c, false);
}
#else
__device__ __forceinline__ float dot2b(u32 a, u32 b, float c){
  c = fmaf(b2f_lo(a), b2f_lo(b), c);
  return fmaf(b2f_hi(a), b2f_hi(b), c);
}
#endif

// ---- MFMA plumbing ----
typedef __attribute__((ext_vector_type(8))) short short8;
typedef __attribute__((ext_vector_type(4))) float f32x4;
__device__ __forceinline__ f32x4 mf32(uint4 a, uint4 b, f32x4 c){
  return __builtin_amdgcn_mfma_f32_16x16x32_bf16(
      __builtin_bit_cast(short8, a), __builtin_bit_cast(short8, b), c, 0, 0, 0);
}

// pre-transposed weight layout offsets in u16 units (padded, zero-filled)
#define OFF_WANG_V 0        // [128][40]
#define OFF_W1_V   5120     // [64][40]
#define OFF_WLIN_V 7680     // [128][136]
#define OFF_W2_V   25088    // [128][72]
#define OFF_WANG_K 34304    // [128][40]
#define OFF_W1_K   39424    // [64][40]
#define OFF_WLIN_K 41984    // [64][136]
#define OFF_W2_K   50688    // [64][72]
#define OFF_WOUT   55296    // [128][136]
#define OFF_WQD    72704    // [64][136]  (Wq @ blockdiag(Wdot))^T
#define WT_TOTAL   81408

__global__ __launch_bounds__(256) void zero_kernel(int* __restrict__ counts,
                                                   int* __restrict__ edge_ids)
{
  int i = blockIdx.x * 256 + threadIdx.x;
  if (i < NN) counts[i] = 0;
  if (i < NE) edge_ids[i] = 0;
}

// ---------------- one-time weight transpose/pad/bf16 prep
__global__ __launch_bounds__(256) void prep_w_kernel(
    const float* __restrict__ Wang_v, const float* __restrict__ W1_v,
    const float* __restrict__ Wlin_v, const float* __restrict__ W2_v,
    const float* __restrict__ Wang_k, const float* __restrict__ W1_k,
    const float* __restrict__ Wlin_k, const float* __restrict__ W2_k,
    const float* __restrict__ Wout, const float* __restrict__ Wq,
    const float* __restrict__ Wdot,
    u16* __restrict__ wt)
{
  int idx = blockIdx.x * 256 + threadIdx.x;
  if (idx >= WT_TOTAL) return;
  float val = 0.f;
  if (idx < OFF_W1_V) {
    int l = idx - OFF_WANG_V, n = l / 40, k = l % 40;
    if (k < 16) val = Wang_v[n * 16 + k];
  } else if (idx < OFF_WLIN_V) {
    int l = idx - OFF_W1_V, n = l / 40, k = l % 40;
    if (k < 16) val = W1_v[k * 64 + n];
  } else if (idx < OFF_W2_V) {
    int l = idx - OFF_WLIN_V, n = l / 136, k = l % 136;
    if (k < 128) val = Wlin_v[k * 128 + n];
  } else if (idx < OFF_WANG_K) {
    int l = idx - OFF_W2_V, n = l / 72, k = l % 72;
    if (k < 64) val = W2_v[k * 128 + n];
  } else if (idx < OFF_W1_K) {
    int l = idx - OFF_WANG_K, n = l / 40, k = l % 40;
    if (k < 16) val = Wang_k[n * 16 + k];
  } else if (idx < OFF_WLIN_K) {
    int l = idx - OFF_W1_K, n = l / 40, k = l % 40;
    if (k < 16) val = W1_k[k * 64 + n];
  } else if (idx < OFF_W2_K) {
    int l = idx - OFF_WLIN_K, n = l / 136, k = l % 136;
    if (k < 128) val = Wlin_k[k * 64 + n];
  } else if (idx < OFF_WOUT) {
    int l = idx - OFF_W2_K, n = l / 72, k = l % 72;
    if (k < 64) val = W2_k[k * 64 + n];
  } else if (idx < OFF_WQD) {                // WoutT: B^T[n][k] = Wout[k*128+n]
    int l = idx - OFF_WOUT, n = l / 136, k = l % 136;
    if (k < 128) val = Wout[k * 128 + n];
  } else {                                   // WqdT[n][k] = sum_i Wq[k,h*8+i]*Wdot[i,r]
    int l = idx - OFF_WQD, n = l / 136, k = l % 136;
    if (k < 128) {
      int h = n >> 3, r = n & 7;
      float s = 0.f;
#pragma unroll
      for (int i = 0; i < 8; ++i) s += Wq[k * 64 + h * 8 + i] * Wdot[i * 8 + r];
      val = s;
    }
  }
  wt[idx] = f2b(val);
}

// ---------------- qw = node_attr @ Wqd, MFMA, 64 nodes/block
__global__ __launch_bounds__(256) void qw_kernel(const float* __restrict__ node_attr,
                                                 const u16* __restrict__ wt,
                                                 u16* __restrict__ qw)
{
  __shared__ __align__(16) u16 sX[64 * 136];
  uint4* sX4 = (uint4*)sX;
  u32* sX32 = (u32*)sX;
  const uint4* wt4 = (const uint4*)wt;
  const int tid = threadIdx.x, wv = tid >> 6, lane = tid & 63, lq = lane >> 4, ln = lane & 15;
  const int n0 = blockIdx.x * 64;
  // B-fragments for cols wv*16+ln
  uint4 rB[4];
#pragma unroll
  for (int ks = 0; ks < 4; ++ks) rB[ks] = wt4[9088 + (wv * 16 + ln) * 17 + ks * 4 + lq];
  // stage X: 64 rows x 128 cols fp32 -> bf16, pitch 136 u16
  {
    int row = tid >> 2, q4 = tid & 3;
    int n = n0 + row;
    bool valid = n < NN;
    const float4* xp = (const float4*)(node_attr + (size_t)(valid ? n : 0) * 128);
#pragma unroll
    for (int i = 0; i < 8; ++i) {
      float4 v = valid ? xp[q4 * 8 + i] : make_float4(0.f, 0.f, 0.f, 0.f);
      sX32[row * 68 + (q4 * 8 + i) * 2]     = packb(v.x, v.y);
      sX32[row * 68 + (q4 * 8 + i) * 2 + 1] = packb(v.z, v.w);
    }
  }
  __syncthreads();
  const f32x4 z4 = {0.f, 0.f, 0.f, 0.f};
  int col = wv * 16 + ln;
#pragma unroll
  for (int et = 0; et < 4; ++et) {
    f32x4 acc = z4;
#pragma unroll
    for (int ks = 0; ks < 4; ++ks) acc = mf32(sX4[(et * 16 + ln) * 17 + ks * 4 + lq], rB[ks], acc);
#pragma unroll
    for (int r = 0; r < 4; ++r) {
      int rr = n0 + et * 16 + lq * 4 + r;
      if (rr < NN) qw[(size_t)rr * 64 + col] = f2b(acc[r]);
    }
  }
}

// ---------------- fused MFMA conv (v and k paths) + alpha, weights in registers
__global__ __launch_bounds__(256, 2) void conv_fused_kernel(
    const float* __restrict__ node_attr, const float* __restrict__ edge_attr,
    const float* __restrict__ edge_sh, const int* __restrict__ edge_index,
    const float* __restrict__ b1v, const float* __restrict__ b1k,
    const u16* __restrict__ wt, const u16* __restrict__ qw,
    u16* __restrict__ v_out, float* __restrict__ alpha)
{
  __shared__ __align__(16) u16 sE[5120];       // EA[64][40] | SH[64][40]; later C_k[64][72]
  __shared__ __align__(16) u16 sTv[64 * 136];
  __shared__ __align__(16) u16 sTk[64 * 136];
  __shared__ __align__(16) u16 sHv[64 * 72];
  __shared__ __align__(16) u16 sHk[64 * 72];
  uint4* sE4 = (uint4*)sE;   u32* sE32 = (u32*)sE;
  uint4* sTv4 = (uint4*)sTv; uint4* sTk4 = (uint4*)sTk;
  uint4* sHv4 = (uint4*)sHv; uint4* sHk4 = (uint4*)sHk;
  const uint4* wt4 = (const uint4*)wt;

  const int tid = threadIdx.x;
  const int wv = tid >> 6, lane = tid & 63, lq = lane >> 4, ln = lane & 15;
  const int e0 = blockIdx.x * 64;
  const int nA = wv * 16 + ln, nB = (wv + 4) * 16 + ln;

  int el = tid >> 2, p = tid & 3;
  int dq = edge_index[NE + e0 + el]; if ((u32)dq >= NN) dq = 0;
  const uint4* qptr = (const uint4*)(qw + (size_t)dq * 64 + p * 16);
  uint4 q0 = qptr[0], q1 = qptr[1];

  uint4 rWangV0 = wt4[nA * 5 + lq],        rWangV1 = wt4[nB * 5 + lq];
  uint4 rW1V    = wt4[640 + nA * 5 + lq];
  uint4 rWangK0 = wt4[4288 + nA * 5 + lq], rWangK1 = wt4[4288 + nB * 5 + lq];
  uint4 rW1K    = wt4[4928 + nA * 5 + lq];
  uint4 rWlinV[2][4], rWlinK[4], rW2V[2][2], rW2K[2];
#pragma unroll
  for (int ks = 0; ks < 4; ++ks) {
    rWlinV[0][ks] = wt4[960 + nA * 17 + ks * 4 + lq];
    rWlinV[1][ks] = wt4[960 + nB * 17 + ks * 4 + lq];
    rWlinK[ks]    = wt4[5248 + nA * 17 + ks * 4 + lq];
  }
#pragma unroll
  for (int ks = 0; ks < 2; ++ks) {
    rW2V[0][ks] = wt4[3136 + nA * 9 + ks * 4 + lq];
    rW2V[1][ks] = wt4[3136 + nB * 9 + ks * 4 + lq];
    rW2K[ks]    = wt4[6336 + nA * 9 + ks * 4 + lq];
  }
  float biasV = b1v[nA], biasK = b1k[nA];

  int srcs[4][4];
#pragma unroll
  for (int et = 0; et < 4; ++et)
#pragma unroll
    for (int r = 0; r < 4; ++r) {
      int s = edge_index[e0 + et * 16 + lq * 4 + r];
      if ((u32)s >= NN) s = 0;
      srcs[et][r] = s;
    }
  float xf[2][4][4];
#pragma unroll
  for (int c = 0; c < 2; ++c) {
    int col = (wv + 4 * c) * 16 + ln;
#pragma unroll
    for (int et = 0; et < 4; ++et)
#pragma unroll
      for (int r = 0; r < 4; ++r)
        xf[c][et][r] = node_attr[(size_t)srcs[et][r] * 128 + col];
  }

  {
    int r = tid >> 2, kq = tid & 3;
    float4 ea = ((const float4*)(edge_attr + (size_t)(e0 + r) * 16))[kq];
    sE32[r * 20 + kq * 2]     = packb(ea.x, ea.y);
    sE32[r * 20 + kq * 2 + 1] = packb(ea.z, ea.w);
    sE32[r * 20 + 8 + kq]  = 0;
    sE32[r * 20 + 12 + kq] = 0;
    float4 sh = ((const float4*)(edge_sh + (size_t)(e0 + r) * 16))[kq];
    sE32[1280 + r * 20 + kq * 2]     = packb(sh.x, sh.y);
    sE32[1280 + r * 20 + kq * 2 + 1] = packb(sh.z, sh.w);
    sE32[1280 + r * 20 + 8 + kq]  = 0;
    sE32[1280 + r * 20 + 12 + kq] = 0;
  }
  __syncthreads();

  const f32x4 z4 = {0.f, 0.f, 0.f, 0.f};
#pragma unroll
  for (int et = 0; et < 4; ++et) {
    uint4 aE = sE4[(et * 16 + ln) * 5 + lq];
    uint4 aS = sE4[320 + (et * 16 + ln) * 5 + lq];
    f32x4 hv = mf32(aE, rW1V, z4);
    f32x4 hk = mf32(aE, rW1K, z4);
    f32x4 t0v = mf32(aS, rWangV0, z4);
    f32x4 t1v = mf32(aS, rWangV1, z4);
    f32x4 t0k = mf32(aS, rWangK0, z4);
    f32x4 t1k = mf32(aS, rWangK1, z4);
    int rowb = et * 16 + lq * 4;
#pragma unroll
    for (int r = 0; r < 4; ++r) {
      sHv[(rowb + r) * 72 + nA] = f2b(fmaxf(hv[r] + biasV, 0.f));
      sHk[(rowb + r) * 72 + nA] = f2b(fmaxf(hk[r] + biasK, 0.f));
      sTv[(rowb + r) * 136 + nA] = f2b(t0v[r] * xf[0][et][r]);
      sTv[(rowb + r) * 136 + nB] = f2b(t1v[r] * xf[1][et][r]);
      sTk[(rowb + r) * 136 + nA] = f2b(t0k[r] * xf[0][et][r]);
      sTk[(rowb + r) * 136 + nB] = f2b(t1k[r] * xf[1][et][r]);
    }
  }
  __syncthreads();

  f32x4 a1v[2][4], a2v[2][4], a1k[4], a2k[4];
#pragma unroll
  for (int et = 0; et < 4; ++et) {
    int ar = et * 16 + ln;
    f32x4 acc;
    acc = z4;
#pragma unroll
    for (int ks = 0; ks < 4; ++ks) acc = mf32(sTv4[ar * 17 + ks * 4 + lq], rWlinV[0][ks], acc);
    a1v[0][et] = acc;
    acc = z4;
#pragma unroll
    for (int ks = 0; ks < 4; ++ks) acc = mf32(sTv4[ar * 17 + ks * 4 + lq], rWlinV[1][ks], acc);
    a1v[1][et] = acc;
    acc = z4;
#pragma unroll
    for (int ks = 0; ks < 4; ++ks) acc = mf32(sTk4[ar * 17 + ks * 4 + lq], rWlinK[ks], acc);
    a1k[et] = acc;
    acc = z4;
#pragma unroll
    for (int ks = 0; ks < 2; ++ks) acc = mf32(sHv4[ar * 9 + ks * 4 + lq], rW2V[0][ks], acc);
    a2v[0][et] = acc;
    acc = z4;
#pragma unroll
    for (int ks = 0; ks < 2; ++ks) acc = mf32(sHv4[ar * 9 + ks * 4 + lq], rW2V[1][ks], acc);
    a2v[1][et] = acc;
    acc = z4;
#pragma unroll
    for (int ks = 0; ks < 2; ++ks) acc = mf32(sHk4[ar * 9 + ks * 4 + lq], rW2K[ks], acc);
    a2k[et] = acc;
  }
  __syncthreads();

#pragma unroll
  for (int et = 0; et < 4; ++et) {
    int rowb = et * 16 + lq * 4;
#pragma unroll
    for (int r = 0; r < 4; ++r) {
      sTv[(rowb + r) * 136 + nA] = f2b(a1v[0][et][r] * a2v[0][et][r]);
      sTv[(rowb + r) * 136 + nB] = f2b(a1v[1][et][r] * a2v[1][et][r]);
      sE[(rowb + r) * 72 + nA]   = f2b(a1k[et][r] * a2k[et][r]);
    }
  }
  __syncthreads();

  {
    int row = tid >> 2, seg = tid & 3;
    uint4* gp = (uint4*)(v_out + (size_t)(e0 + row) * 128);
#pragma unroll
    for (int i = 0; i < 4; ++i) gp[seg * 4 + i] = sTv4[row * 17 + seg * 4 + i];
  }
  {
    uint4 k0 = sE4[el * 9 + p * 2];
    uint4 k1 = sE4[el * 9 + p * 2 + 1];
    float a0 = 0.f, a1 = 0.f;
    a0 = dot2b(q0.x, k0.x, a0); a0 = dot2b(q0.y, k0.y, a0);
    a0 = dot2b(q0.z, k0.z, a0); a0 = dot2b(q0.w, k0.w, a0);
    a1 = dot2b(q1.x, k1.x, a1); a1 = dot2b(q1.y, k1.y, a1);
    a1 = dot2b(q1.z, k1.z, a1); a1 = dot2b(q1.w, k1.w, a1);
    ((float2*)(alpha + (size_t)(e0 + el) * 8))[p] = make_float2(a0, a1);
  }
}

// ---------------- CSR build
__global__ __launch_bounds__(256) void count_kernel(const int* __restrict__ edge_index,
                                                    int* __restrict__ counts)
{
  int e = blockIdx.x * 256 + threadIdx.x;
  if (e < NE) { int d = edge_index[NE + e]; if ((u32)d >= NN) d = 0; atomicAdd(&counts[d], 1); }
}

__global__ __launch_bounds__(1024) void scan_kernel(const int* __restrict__ counts,
                                                    int* __restrict__ row_ptr,
                                                    int* __restrict__ cursor)
{
  __shared__ int s[1024];
  int tid = threadIdx.x;
  int base = tid * STRIP;
  int sum = 0;
  for (int i = 0; i < STRIP; ++i) { int idx = base + i; sum += (idx < NN) ? counts[idx] : 0; }
  s[tid] = sum;
  __syncthreads();
  for (int off = 1; off < 1024; off <<= 1) {
    int v = s[tid];
    int add = (tid >= off) ? s[tid - off] : 0;
    __syncthreads();
    s[tid] = v + add;
    __syncthreads();
  }
  int running = (tid == 0) ? 0 : s[tid - 1];
  for (int i = 0; i < STRIP; ++i) {
    int idx = base + i;
    if (idx < NN) { row_ptr[idx] = running; cursor[idx] = running; running += counts[idx]; }
  }
  if (tid == 1023) row_ptr[NN] = running;
}

__global__ __launch_bounds__(256) void fill_kernel(const int* __restrict__ edge_index,
                                                   int* __restrict__ cursor,
                                                   int* __restrict__ edge_ids)
{
  int e = blockIdx.x * 256 + threadIdx.x;
  if (e < NE) {
    int dst = edge_index[NE + e]; if ((u32)dst >= NN) dst = 0;
    int pos = atomicAdd(&cursor[dst], 1);
    if ((u32)pos < NE) edge_ids[pos] = e;
  }
}

// ---------------- per-node single-pass online softmax + V gather (u32 loads,
// 4x unrolled) + MFMA @Wout epilogue. One wave per node, 16 nodes per block.
#define OUPD(aa, ww)                                                   \
  { float mn = fmaxf(m, (aa));                                         \
    float sc = __expf(m - mn);                                         \
    float pw = __expf((aa) - mn);                                      \
    l = l * sc + pw;                                                   \
    accA = accA * sc + pw * b2f_lo(ww);                                \
    accB = accB * sc + pw * b2f_hi(ww);                                \
    m = mn; }

__global__ __launch_bounds__(256) void out_kernel(
    const int* __restrict__ row_ptr, const int* __restrict__ edge_ids,
    const float* __restrict__ alpha, const u16* __restrict__ v_e,
    const u16* __restrict__ wt, float* __restrict__ out)
{
  __shared__ __align__(16) u16 sAgg[16 * 136];
  u32* sAgg32 = (u32*)sAgg;
  uint4* sAgg4 = (uint4*)sAgg;
  const uint4* wt4 = (const uint4*)wt;
  const u32* v32 = (const u32*)v_e;
  const int tid = threadIdx.x, wv = tid >> 6, lane = tid & 63, lq = lane >> 4, ln = lane & 15;
  const f32x4 z4 = {0.f, 0.f, 0.f, 0.f};
  uint4 rWT[2][4];
#pragma unroll
  for (int c = 0; c < 2; ++c) {
    int n = (wv * 2 + c) * 16 + ln;
#pragma unroll
    for (int ks = 0; ks < 4; ++ks) rWT[c][ks] = wt4[6912 + n * 17 + ks * 4 + lq];
  }
  const int hh = lane >> 3;   // head of cols {2*lane, 2*lane+1}
  const int grp = blockIdx.x;
#pragma unroll 1
  for (int i = 0; i < 4; ++i) {
    int n = grp * 16 + wv * 4 + i;
    int beg = row_ptr[n], end = row_ptr[n + 1];
    if (beg < 0) beg = 0; if (beg > NE) beg = NE;
    if (end < beg) end = beg; if (end > NE) end = NE;
    int deg = end - beg;
    float m = -3.0e38f, l = 0.f, accA = 0.f, accB = 0.f;
    int j = 0;
#pragma unroll 1
    for (; j + 4 <= deg; j += 4) {
      int e0 = edge_ids[beg + j],     e1 = edge_ids[beg + j + 1];
      int e2 = edge_ids[beg + j + 2], e3 = edge_ids[beg + j + 3];
      if ((u32)e0 >= NE) e0 = 0; if ((u32)e1 >= NE) e1 = 0;
      if ((u32)e2 >= NE) e2 = 0; if ((u32)e3 >= NE) e3 = 0;
      float a0 = alpha[(size_t)e0 * 8 + hh]; u32 w0 = v32[(size_t)e0 * 64 + lane];
      float a1 = alpha[(size_t)e1 * 8 + hh]; u32 w1 = v32[(size_t)e1 * 64 + lane];
      float a2 = alpha[(size_t)e2 * 8 + hh]; u32 w2 = v32[(size_t)e2 * 64 + lane];
      float a3 = alpha[(size_t)e3 * 8 + hh]; u32 w3 = v32[(size_t)e3 * 64 + lane];
      OUPD(a0, w0); OUPD(a1, w1); OUPD(a2, w2); OUPD(a3, w3);
    }
#pragma unroll 1
    for (; j < deg; ++j) {
      int e = edge_ids[beg + j]; if ((u32)e >= NE) e = 0;
      float a = alpha[(size_t)e * 8 + hh]; u32 w = v32[(size_t)e * 64 + lane];
      OUPD(a, w);
    }
    float inv = (l > 0.f) ? (1.f / l) : 0.f;
    accA *= inv; accB *= inv;
    sAgg32[(wv * 4 + i) * 68 + lane] = packb(accA, accB);
  }
  __syncthreads();
#pragma unroll
  for (int c = 0; c < 2; ++c) {
    f32x4 acc = z4;
#pragma unroll
    for (int ks = 0; ks < 4; ++ks) acc = mf32(sAgg4[ln * 17 + ks * 4 + lq], rWT[c][ks], acc);
    int col = (wv * 2 + c) * 16 + ln;
#pragma unroll
    for (int r = 0; r < 4; ++r)
      out[(size_t)(grp * 16 + lq * 4 + r) * 128 + col] = acc[r];
  }
}

extern "C" void kernel_launch(void* const* d_in, const int* in_sizes, int n_in,
                              void* d_out, int out_size, void* d_ws, size_t ws_size,
                              hipStream_t stream)
{
  const float* node_attr = (const float*)d_in[0];
  const float* edge_attr = (const float*)d_in[1];
  const float* edge_sh   = (const float*)d_in[2];
  const float* Wq        = (const float*)d_in[3];
  const float* Wang_k    = (const float*)d_in[4];
  const float* Wlin_k    = (const float*)d_in[5];
  const float* W1k       = (const float*)d_in[6];
  const float* b1k       = (const float*)d_in[7];
  const float* W2k       = (const float*)d_in[8];
  const float* Wang_v    = (const float*)d_in[9];
  const float* Wlin_v    = (const float*)d_in[10];
  const float* W1v       = (const float*)d_in[11];
  const float* b1v       = (const float*)d_in[12];
  const float* W2v       = (const float*)d_in[13];
  const float* Wdot      = (const float*)d_in[14];
  const float* Wout      = (const float*)d_in[15];
  const int* edge_index  = (const int*)d_in[16];
  float* out = (float*)d_out;

  char* ws = (char*)d_ws;
  u16*   v_e      = (u16*)(ws + 0);                 // E*128*2  = 204,800,000
  float* alpha    = (float*)(ws + 204800000);       // E*8*4    =  25,600,000
  u16*   qw       = (u16*)(ws + 230400000);         // N*64*2   =   6,400,000
  int*   counts   = (int*)(ws + 236800000);         // 200,064
  int*   row_ptr  = (int*)(ws + 237000064);         // 200,064
  int*   cursor   = (int*)(ws + 237200128);         // 200,064
  int*   edge_ids = (int*)(ws + 237400192);         // 3,200,000
  u16*   wt       = (u16*)(ws + 240600192);         // 162,816 -> total 240,763,008

  zero_kernel<<<dim3((NE + 255) / 256), dim3(256), 0, stream>>>(counts, edge_ids);
  prep_w_kernel<<<dim3((WT_TOTAL + 255) / 256), dim3(256), 0, stream>>>(
      Wang_v, W1v, Wlin_v, W2v, Wang_k, W1k, Wlin_k, W2k, Wout, Wq, Wdot, wt);
  qw_kernel<<<dim3((NN + 63) / 64), dim3(256), 0, stream>>>(node_attr, wt, qw);
  conv_fused_kernel<<<dim3(NE / 64), dim3(256), 0, stream>>>(
      node_attr, edge_attr, edge_sh, edge_index, b1v, b1k, wt, qw, v_e, alpha);
  count_kernel<<<dim3((NE + 255) / 256), dim3(256), 0, stream>>>(edge_index, counts);
  scan_kernel<<<dim3(1), dim3(1024), 0, stream>>>(counts, row_ptr, cursor);
  fill_kernel<<<dim3((NE + 255) / 256), dim3(256), 0, stream>>>(edge_index, cursor, edge_ids);
  out_kernel<<<dim3(3125), dim3(256), 0, stream>>>(row_ptr, edge_ids, alpha, v_e, wt, out);
}